// Round 2
// baseline (13840.646 us; speedup 1.0000x reference)
//
#include <hip/hip_runtime.h>
#include <hip/hip_bf16.h>

typedef __hip_bfloat16 bf16;

#define DEV __device__ __forceinline__

struct __align__(16) bf16x8 { bf16 h[8]; };

DEV float wave_sum(float v) {
    #pragma unroll
    for (int m = 1; m < 64; m <<= 1) v += __shfl_xor(v, m);
    return v;
}

// ---------------------------------------------------------------------------
// Layer 1: complex conv 2 -> 32(+32), input x is (B, 64, 64, 2) NHWC float32.
// Output t1: (B, 64, 64, 64) bf16, ch o = cr-ci, ch 32+o = cr+ci.
// ---------------------------------------------------------------------------
__global__ __launch_bounds__(256) void conv1_k(
    const float* __restrict__ x,
    const float* __restrict__ w1r, const float* __restrict__ b1r,
    const float* __restrict__ w1i, const float* __restrict__ b1i,
    bf16* __restrict__ out)
{
    int idx = blockIdx.x * 256 + threadIdx.x;      // b*4096 + m*64 + n
    int b = idx >> 12, p = idx & 4095;
    int m = p >> 6, n = p & 63;

    float v[2][9];
    #pragma unroll
    for (int dy = 0; dy < 3; ++dy)
        #pragma unroll
        for (int dx = 0; dx < 3; ++dx) {
            int yy = m + dy - 1, xx = n + dx - 1;
            bool ok = (yy >= 0 && yy < 64 && xx >= 0 && xx < 64);
            int base = ((b * 64 + (ok ? yy : 0)) * 64 + (ok ? xx : 0)) * 2;
            v[0][dy*3+dx] = ok ? x[base]     : 0.f;
            v[1][dy*3+dx] = ok ? x[base + 1] : 0.f;
        }

    bf16* ob = out + (size_t)b * 64 * 4096 + p;
    #pragma unroll
    for (int o = 0; o < 32; ++o) {
        float cr = b1r[o], ci = b1i[o];
        #pragma unroll
        for (int c = 0; c < 2; ++c)
            #pragma unroll
            for (int k = 0; k < 9; ++k) {
                cr = fmaf(v[c][k], w1r[(o*2+c)*9 + k], cr);
                ci = fmaf(v[c][k], w1i[(o*2+c)*9 + k], ci);
            }
        ob[(size_t)o        * 4096] = __float2bfloat16(cr - ci);
        ob[(size_t)(32 + o) * 4096] = __float2bfloat16(cr + ci);
    }
}

// ---------------------------------------------------------------------------
// Complex conv CIN -> COUT(+COUT), LDS-tiled 16x16 spatial, 16 o per block.
// in: (nb, CIN, 64, 64) bf16 ; out: (nb, 2*COUT, 64, 64) bf16
// grid: (16 tiles, COUT/16, nb), block 256.
// ---------------------------------------------------------------------------
template<int CIN>
__global__ __launch_bounds__(256) void convc_k(
    const bf16* __restrict__ in,
    const float* __restrict__ wr, const float* __restrict__ br,
    const float* __restrict__ wi, const float* __restrict__ bi,
    bf16* __restrict__ out, int COUT)
{
    const int tile = blockIdx.x;
    const int ty0 = (tile >> 2) * 16, tx0 = (tile & 3) * 16;
    const int cb = blockIdx.y;
    const int b  = blockIdx.z;
    const int o0 = cb * 16;

    const int t  = threadIdx.x;
    const int px = t & 15, py = t >> 4;
    const int gy = ty0 + py, gx = tx0 + px;

    __shared__ bf16 smem[4][18][18];

    float accr[16], acci[16];
    #pragma unroll
    for (int o = 0; o < 16; ++o) { accr[o] = br[o0+o]; acci[o] = bi[o0+o]; }

    const bf16* inb = in + (size_t)b * CIN * 4096;

    for (int c0 = 0; c0 < CIN; c0 += 4) {
        __syncthreads();
        for (int e = t; e < 4*324; e += 256) {
            int cl  = e / 324;
            int rem = e - cl * 324;
            int iy  = rem / 18, ix = rem - iy * 18;
            int yy = ty0 + iy - 1, xx = tx0 + ix - 1;
            bf16 hv = __float2bfloat16(0.f);
            if (yy >= 0 && yy < 64 && xx >= 0 && xx < 64)
                hv = inb[(size_t)(c0 + cl) * 4096 + yy * 64 + xx];
            smem[cl][iy][ix] = hv;
        }
        __syncthreads();
        #pragma unroll
        for (int cl = 0; cl < 4; ++cl) {
            float v[9];
            #pragma unroll
            for (int dy = 0; dy < 3; ++dy)
                #pragma unroll
                for (int dx = 0; dx < 3; ++dx)
                    v[dy*3+dx] = __bfloat162float(smem[cl][py+dy][px+dx]);
            const float* wrp = wr + ((size_t)o0 * CIN + (c0 + cl)) * 9;
            const float* wip = wi + ((size_t)o0 * CIN + (c0 + cl)) * 9;
            #pragma unroll
            for (int o = 0; o < 16; ++o) {
                #pragma unroll
                for (int k = 0; k < 9; ++k) {
                    accr[o] = fmaf(v[k], wrp[o*CIN*9 + k], accr[o]);
                    acci[o] = fmaf(v[k], wip[o*CIN*9 + k], acci[o]);
                }
            }
        }
    }

    bf16* ob = out + (size_t)b * 2 * COUT * 4096 + gy * 64 + gx;
    #pragma unroll
    for (int o = 0; o < 16; ++o) {
        ob[(size_t)(o0 + o)        * 4096] = __float2bfloat16(accr[o] - acci[o]);
        ob[(size_t)(COUT + o0 + o) * 4096] = __float2bfloat16(accr[o] + acci[o]);
    }
}

// ---------------------------------------------------------------------------
// Same conv, but no store: per-channel sum/sumsq block-reduced + atomicAdd.
// stats layout: [0, 2*COUT) sums, [2*COUT, 4*COUT) sumsq.
// ---------------------------------------------------------------------------
template<int CIN>
__global__ __launch_bounds__(256) void convc_stats_k(
    const bf16* __restrict__ in,
    const float* __restrict__ wr, const float* __restrict__ br,
    const float* __restrict__ wi, const float* __restrict__ bi,
    float* __restrict__ stats, int COUT)
{
    const int tile = blockIdx.x;
    const int ty0 = (tile >> 2) * 16, tx0 = (tile & 3) * 16;
    const int cb = blockIdx.y;
    const int b  = blockIdx.z;
    const int o0 = cb * 16;

    const int t  = threadIdx.x;
    const int px = t & 15, py = t >> 4;

    __shared__ bf16 smem[4][18][18];
    __shared__ float l4[4][4];

    float accr[16], acci[16];
    #pragma unroll
    for (int o = 0; o < 16; ++o) { accr[o] = br[o0+o]; acci[o] = bi[o0+o]; }

    const bf16* inb = in + (size_t)b * CIN * 4096;

    for (int c0 = 0; c0 < CIN; c0 += 4) {
        __syncthreads();
        for (int e = t; e < 4*324; e += 256) {
            int cl  = e / 324;
            int rem = e - cl * 324;
            int iy  = rem / 18, ix = rem - iy * 18;
            int yy = ty0 + iy - 1, xx = tx0 + ix - 1;
            bf16 hv = __float2bfloat16(0.f);
            if (yy >= 0 && yy < 64 && xx >= 0 && xx < 64)
                hv = inb[(size_t)(c0 + cl) * 4096 + yy * 64 + xx];
            smem[cl][iy][ix] = hv;
        }
        __syncthreads();
        #pragma unroll
        for (int cl = 0; cl < 4; ++cl) {
            float v[9];
            #pragma unroll
            for (int dy = 0; dy < 3; ++dy)
                #pragma unroll
                for (int dx = 0; dx < 3; ++dx)
                    v[dy*3+dx] = __bfloat162float(smem[cl][py+dy][px+dx]);
            const float* wrp = wr + ((size_t)o0 * CIN + (c0 + cl)) * 9;
            const float* wip = wi + ((size_t)o0 * CIN + (c0 + cl)) * 9;
            #pragma unroll
            for (int o = 0; o < 16; ++o) {
                #pragma unroll
                for (int k = 0; k < 9; ++k) {
                    accr[o] = fmaf(v[k], wrp[o*CIN*9 + k], accr[o]);
                    acci[o] = fmaf(v[k], wip[o*CIN*9 + k], acci[o]);
                }
            }
        }
    }

    const int wid = t >> 6, lane = t & 63;
    #pragma unroll 1
    for (int o = 0; o < 16; ++o) {
        float vA = accr[o] - acci[o], vB = accr[o] + acci[o];
        float sA = wave_sum(vA), qA = wave_sum(vA * vA);
        float sB = wave_sum(vB), qB = wave_sum(vB * vB);
        if (lane == 0) { l4[wid][0]=sA; l4[wid][1]=qA; l4[wid][2]=sB; l4[wid][3]=qB; }
        __syncthreads();
        if (t == 0) {
            float SA = l4[0][0]+l4[1][0]+l4[2][0]+l4[3][0];
            float QA = l4[0][1]+l4[1][1]+l4[2][1]+l4[3][1];
            float SB = l4[0][2]+l4[1][2]+l4[2][2]+l4[3][2];
            float QB = l4[0][3]+l4[1][3]+l4[2][3]+l4[3][3];
            int chA = o0 + o, chB = COUT + o0 + o;
            atomicAdd(&stats[chA], SA);
            atomicAdd(&stats[2*COUT + chA], QA);
            atomicAdd(&stats[chB], SB);
            atomicAdd(&stats[2*COUT + chB], QB);
        }
        __syncthreads();
    }
}

// ---------------------------------------------------------------------------
// Per-channel sum / sumsq over (B, H, W). grid: C*32 blocks, 256 threads.
// ---------------------------------------------------------------------------
__global__ __launch_bounds__(256) void stats_k(
    const bf16* __restrict__ t, float* __restrict__ stats, int C)
{
    int c = blockIdx.x >> 5;
    int chunk = blockIdx.x & 31;
    float s = 0.f, s2 = 0.f;
    #pragma unroll 4
    for (int i = 0; i < 64; ++i) {
        int e = chunk * 16384 + i * 256 + threadIdx.x;   // [0, 524288)
        int b = e >> 12, p = e & 4095;
        float v = __bfloat162float(t[((size_t)(b * C + c)) * 4096 + p]);
        s += v; s2 += v * v;
    }
    s = wave_sum(s); s2 = wave_sum(s2);
    __shared__ float ls[4], ls2[4];
    int wid = threadIdx.x >> 6;
    if ((threadIdx.x & 63) == 0) { ls[wid] = s; ls2[wid] = s2; }
    __syncthreads();
    if (threadIdx.x == 0) {
        atomicAdd(&stats[c],     ls[0]+ls[1]+ls[2]+ls[3]);
        atomicAdd(&stats[C + c], ls2[0]+ls2[1]+ls2[2]+ls2[3]);
    }
}

__global__ void bnparam_k(const float* __restrict__ stats,
                          const float* __restrict__ g, const float* __restrict__ be,
                          float* __restrict__ sc, int C)
{
    int c = threadIdx.x;
    if (c >= C) return;
    const float invN = 1.f / (128.f * 4096.f);
    float mean  = stats[c] * invN;
    float var   = stats[C + c] * invN - mean * mean;
    float scale = g[c] * rsqrtf(var + 1e-5f);
    sc[c]     = scale;
    sc[C + c] = be[c] - mean * scale;
}

// in-place BN + relu, 8 bf16 per thread
__global__ __launch_bounds__(256) void bnapply_k(
    bf16* __restrict__ t, const float* __restrict__ sc, int C, int total8)
{
    int i = blockIdx.x * 256 + threadIdx.x;
    if (i >= total8) return;
    size_t e = (size_t)i * 8;
    int c = (int)((e >> 12) & (size_t)(C - 1));
    float scale = sc[c], shift = sc[C + c];
    bf16x8 r = *reinterpret_cast<const bf16x8*>(t + e);
    #pragma unroll
    for (int k = 0; k < 8; ++k) {
        float v = fmaxf(fmaf(__bfloat162float(r.h[k]), scale, shift), 0.f);
        r.h[k] = __float2bfloat16(v);
    }
    *reinterpret_cast<bf16x8*>(t + e) = r;
}

// ---------------------------------------------------------------------------
// Fused BN+relu + pooling for layer 3. One wave per (b, c). C == 256.
// pu[b][c][m] = row mean, pv[b][c][n] = col mean, ps[b][c] = total mean.
// Pointers may be pre-offset for batch chunking; blockIdx.x covers nb*256.
// ---------------------------------------------------------------------------
__global__ __launch_bounds__(64) void pool3_k(
    const bf16* __restrict__ t3, const float* __restrict__ sc,
    float* __restrict__ pu, float* __restrict__ pv, float* __restrict__ ps)
{
    int bc = blockIdx.x;              // b*256 + c (b local to chunk)
    int c = bc & 255, lane = threadIdx.x;
    float scale = sc[c], shift = sc[256 + c];
    const bf16* p = t3 + (size_t)bc * 4096;
    float colsum = 0.f, myrow = 0.f;
    for (int m = 0; m < 64; ++m) {
        float v = fmaxf(fmaf(__bfloat162float(p[m*64 + lane]), scale, shift), 0.f);
        colsum += v;
        float r = wave_sum(v);
        if (lane == m) myrow = r;
    }
    pu[(size_t)bc * 64 + lane] = myrow  * (1.f/64.f);
    pv[(size_t)bc * 64 + lane] = colsum * (1.f/64.f);
    float tot = wave_sum(colsum);
    if (lane == 0) ps[bc] = tot * (1.f/4096.f);
}

// u/v head: out[b][o][m] = relu(sum_c pool[b][c][m] * w[o][c] + bias[o]), o<16
__global__ __launch_bounds__(256) void headuv_k(
    const float* __restrict__ pool, const float* __restrict__ w,
    const float* __restrict__ bias, float* __restrict__ out)
{
    int b = blockIdx.x;
    int m = threadIdx.x & 63;
    int ob4 = threadIdx.x >> 6;   // 0..3 (wave-uniform)
    float acc[4] = { bias[ob4], bias[ob4+4], bias[ob4+8], bias[ob4+12] };
    const float* pb = pool + (size_t)b * 256 * 64 + m;
    for (int c = 0; c < 256; ++c) {
        float v = pb[c * 64];
        #pragma unroll
        for (int i = 0; i < 4; ++i)
            acc[i] = fmaf(v, w[(ob4 + i*4) * 256 + c], acc[i]);
    }
    float* op = out + (size_t)b * 16 * 64 + m;
    #pragma unroll
    for (int i = 0; i < 4; ++i)
        op[(ob4 + i*4) * 64] = fmaxf(acc[i], 0.f);
}

// s head: out[b][o] = relu(sum_c ps[b][c] * wS[o][c] + bS[o]), o<8
__global__ __launch_bounds__(64) void heads_s_k(
    const float* __restrict__ ps, const float* __restrict__ wS,
    const float* __restrict__ bS, float* __restrict__ out)
{
    int b = blockIdx.x, lane = threadIdx.x;
    float acc[8] = {0,0,0,0,0,0,0,0};
    for (int c = lane; c < 256; c += 64) {
        float v = ps[b * 256 + c];
        #pragma unroll
        for (int o = 0; o < 8; ++o) acc[o] = fmaf(v, wS[o*256 + c], acc[o]);
    }
    #pragma unroll
    for (int o = 0; o < 8; ++o) acc[o] = wave_sum(acc[o]);
    if (lane == 0) {
        #pragma unroll
        for (int o = 0; o < 8; ++o)
            out[b*8 + o] = fmaxf(acc[o] + bS[o], 0.f);
    }
}

// ---------------------------------------------------------------------------
// Gram-Schmidt: one wave per batch, lane = m. pre: (B,16,64), out: (B,64,8,2)
// ---------------------------------------------------------------------------
__global__ __launch_bounds__(64) void gs_k(
    const float* __restrict__ pre, float* __restrict__ out)
{
    int b = blockIdx.x, lane = threadIdx.x;
    const float* pb = pre + (size_t)b * 16 * 64 + lane;
    float vr[8], vi[8], den[8];
    #pragma unroll
    for (int j = 0; j < 8; ++j) { vr[j] = pb[(2*j)*64]; vi[j] = pb[(2*j+1)*64]; }

    #pragma unroll
    for (int j = 0; j < 8; ++j) {
        #pragma unroll
        for (int k = 0; k < j; ++k) {
            float d = wave_sum(vr[j]*vr[k] + vi[j]*vi[k]);
            float coef = d / den[k];
            vr[j] = fmaf(-coef, vr[k], vr[j]);
            vi[j] = fmaf(-coef, vi[k], vi[j]);
        }
        float n2 = wave_sum(vr[j]*vr[j] + vi[j]*vi[j]);
        float inv = 1.f / sqrtf(n2 + 1e-8f);
        vr[j] *= inv; vi[j] *= inv;
        float nn = wave_sum(vr[j]*vr[j] + vi[j]*vi[j]);
        den[j] = nn + 1e-8f;
    }
    float* ob = out + (size_t)b * 64 * 16 + lane * 16;
    #pragma unroll
    for (int j = 0; j < 8; ++j) { ob[j*2] = vr[j]; ob[j*2+1] = vi[j]; }
}

// ---------------------------------------------------------------------------
extern "C" void kernel_launch(void* const* d_in, const int* in_sizes, int n_in,
                              void* d_out, int out_size, void* d_ws, size_t ws_size,
                              hipStream_t stream)
{
    const float* x   = (const float*)d_in[0];
    const float* w1r = (const float*)d_in[1];
    const float* b1r = (const float*)d_in[2];
    const float* w1i = (const float*)d_in[3];
    const float* b1i = (const float*)d_in[4];
    const float* g1  = (const float*)d_in[5];
    const float* be1 = (const float*)d_in[6];
    const float* w2r = (const float*)d_in[7];
    const float* b2r = (const float*)d_in[8];
    const float* w2i = (const float*)d_in[9];
    const float* b2i = (const float*)d_in[10];
    const float* g2  = (const float*)d_in[11];
    const float* be2 = (const float*)d_in[12];
    const float* w3r = (const float*)d_in[13];
    const float* b3r = (const float*)d_in[14];
    const float* w3i = (const float*)d_in[15];
    const float* b3i = (const float*)d_in[16];
    const float* g3  = (const float*)d_in[17];
    const float* be3 = (const float*)d_in[18];
    const float* wu  = (const float*)d_in[19];
    const float* bu  = (const float*)d_in[20];
    const float* wS  = (const float*)d_in[21];
    const float* bS  = (const float*)d_in[22];
    const float* wv  = (const float*)d_in[23];
    const float* bv  = (const float*)d_in[24];
    float* out = (float*)d_out;

    auto al = [](size_t x_) { return (x_ + 255) & ~(size_t)255; };
    const size_t T1 = (size_t)128 * 64  * 4096 * 2;   //  67,108,864
    const size_t T2 = (size_t)128 * 128 * 4096 * 2;   // 134,217,728
    const size_t T3 = (size_t)128 * 256 * 4096 * 2;   // 268,435,456

    char* ws = (char*)d_ws;
    // t2 at 0; t1 after t2; t3 (fast: full 268M, low: 16-batch chunk 33.5M)
    // overlays the dead t1 region once conv2 has consumed t1.
    size_t t2_off = 0;
    size_t t1_off = al(T2);
    size_t smalls = 2 * al((size_t)128*256*64*4) + al((size_t)128*256*4)
                  + 2 * al((size_t)128*16*64*4) + 2 * al(896*4);
    size_t need_fast = t1_off + al(T3) + smalls;   // ~420.6 MB
    bool fast = (ws_size >= need_fast);
    size_t off = fast ? (t1_off + al(T3)) : (t1_off + al(T1));

    bf16* t2 = (bf16*)(ws + t2_off);
    bf16* t1 = (bf16*)(ws + t1_off);
    bf16* t3 = (bf16*)(ws + t1_off);   // full (fast) or chunk buffer (low)

    auto alloc = [&](size_t bytes) { void* p = ws + off; off += al(bytes); return p; };
    float* pu    = (float*)alloc((size_t)128*256*64*4);
    float* pv    = (float*)alloc((size_t)128*256*64*4);
    float* ps    = (float*)alloc((size_t)128*256*4);
    float* upre  = (float*)alloc((size_t)128*16*64*4);
    float* vpre  = (float*)alloc((size_t)128*16*64*4);
    float* stats = (float*)alloc(896*4);   // s1:128f, s2:256f, s3:512f
    float* scsh  = (float*)alloc(896*4);   // sc1:128f, sc2:256f, sc3:512f
    float* stats1 = stats, *stats2 = stats + 128, *stats3 = stats + 384;
    float* sc1 = scsh, *sc2 = scsh + 128, *sc3 = scsh + 384;

    hipMemsetAsync(stats, 0, 896*4, stream);

    // ---- layer 1
    conv1_k<<<2048, 256, 0, stream>>>(x, w1r, b1r, w1i, b1i, t1);
    stats_k<<<64*32, 256, 0, stream>>>(t1, stats1, 64);
    bnparam_k<<<1, 64, 0, stream>>>(stats1, g1, be1, sc1, 64);
    bnapply_k<<<(128*64*4096/8 + 255)/256, 256, 0, stream>>>(t1, sc1, 64, 128*64*4096/8);

    // ---- layer 2
    convc_k<64><<<dim3(16, 4, 128), 256, 0, stream>>>(t1, w2r, b2r, w2i, b2i, t2, 64);
    stats_k<<<128*32, 256, 0, stream>>>(t2, stats2, 128);
    bnparam_k<<<1, 128, 0, stream>>>(stats2, g2, be2, sc2, 128);
    bnapply_k<<<(128*128*4096/8 + 255)/256, 256, 0, stream>>>(t2, sc2, 128, 128*128*4096/8);

    // ---- layer 3 (BN+relu fused into pooling; t1 region is dead now)
    if (fast) {
        convc_k<128><<<dim3(16, 8, 128), 256, 0, stream>>>(t2, w3r, b3r, w3i, b3i, t3, 128);
        stats_k<<<256*32, 256, 0, stream>>>(t3, stats3, 256);
        bnparam_k<<<1, 256, 0, stream>>>(stats3, g3, be3, sc3, 256);
        pool3_k<<<128*256, 64, 0, stream>>>(t3, sc3, pu, pv, ps);
    } else {
        // pass 1: stats only, no store
        convc_stats_k<128><<<dim3(16, 8, 128), 256, 0, stream>>>(t2, w3r, b3r, w3i, b3i, stats3, 128);
        bnparam_k<<<1, 256, 0, stream>>>(stats3, g3, be3, sc3, 256);
        // pass 2: recompute in 8 chunks of 16 batches, pool immediately
        for (int cch = 0; cch < 8; ++cch) {
            const bf16* inb = t2 + (size_t)cch * 16 * 128 * 4096;
            convc_k<128><<<dim3(16, 8, 16), 256, 0, stream>>>(inb, w3r, b3r, w3i, b3i, t3, 128);
            pool3_k<<<16*256, 64, 0, stream>>>(t3, sc3,
                pu + (size_t)cch * 16 * 256 * 64,
                pv + (size_t)cch * 16 * 256 * 64,
                ps + (size_t)cch * 16 * 256);
        }
    }

    // ---- heads
    headuv_k<<<128, 256, 0, stream>>>(pu, wu, bu, upre);
    headuv_k<<<128, 256, 0, stream>>>(pv, wv, bv, vpre);
    heads_s_k<<<128, 64, 0, stream>>>(ps, wS, bS, out + 131072);

    // ---- gram-schmidt
    gs_k<<<128, 64, 0, stream>>>(upre, out);            // u at [0, 131072)
    gs_k<<<128, 64, 0, stream>>>(vpre, out + 132096);   // v at [132096, 263168)
}

// Round 3
// 2553.450 us; speedup vs baseline: 5.4204x; 5.4204x over previous
//
#include <hip/hip_runtime.h>
#include <hip/hip_bf16.h>

typedef __hip_bfloat16 bf16;
typedef __attribute__((ext_vector_type(8))) short short8;
typedef __attribute__((ext_vector_type(4))) float f32x4;

#define DEV __device__ __forceinline__

DEV float bf2f(short s) {
    unsigned int u = ((unsigned int)(unsigned short)s) << 16;
    float f; __builtin_memcpy(&f, &u, 4); return f;
}
DEV short f2bf(float f) {
    __hip_bfloat16 h = __float2bfloat16(f);
    short s; __builtin_memcpy(&s, &h, 2); return s;
}

DEV float wave_sum(float v) {
    #pragma unroll
    for (int m = 1; m < 64; m <<= 1) v += __shfl_xor(v, m);
    return v;
}

// ---------------------------------------------------------------------------
// Weight prep: fold complex conv (wA = wr-wi, wB = wr+wi), split hi/lo bf16,
// pack into MFMA fragment order: flat = (((s*NG+g)*2+ver)*64+lane)*8+j
// where s = tap*KC+kc, n = g*16+(lane&15), cin = kc*32+(lane>>4)*8+j.
// Also folds bias: bf_[n] = br[o] +- bi[o].
// ---------------------------------------------------------------------------
__global__ __launch_bounds__(256) void prep_w_k(
    const float* __restrict__ wr, const float* __restrict__ wi,
    const float* __restrict__ br, const float* __restrict__ bi,
    bf16* __restrict__ wf, float* __restrict__ bf_, int CIN, int COUT)
{
    int idx = blockIdx.x * 256 + threadIdx.x;
    int NOUT = 2 * COUT, KC = CIN >> 5, NG = NOUT >> 4;
    if (idx < NOUT) {
        int o = idx < COUT ? idx : idx - COUT;
        float sgn = idx < COUT ? -1.f : 1.f;
        bf_[idx] = br[o] + sgn * bi[o];
    }
    int total = 9 * KC * NG * 1024;
    if (idx >= total) return;
    int j = idx & 7, lane = (idx >> 3) & 63, ver = (idx >> 9) & 1;
    int t10 = idx >> 10;
    int gg = t10 % NG, s = t10 / NG;
    int kc = s % KC, tap = s / KC;
    int n = gg * 16 + (lane & 15);
    int cin = kc * 32 + (lane >> 4) * 8 + j;
    int o = n < COUT ? n : n - COUT;
    float sgn = n < COUT ? -1.f : 1.f;
    float wv = wr[(o * CIN + cin) * 9 + tap] + sgn * wi[(o * CIN + cin) * 9 + tap];
    __hip_bfloat16 hi = __float2bfloat16(wv);
    float rem = wv - __bfloat162float(hi);
    wf[idx] = ver ? __float2bfloat16(rem) : hi;
}

// ---------------------------------------------------------------------------
// conv1: 2 -> 64 channels, fp32 VALU, NHWC bf16 raw output.
// ---------------------------------------------------------------------------
__global__ __launch_bounds__(256) void conv1_k(
    const float* __restrict__ x,
    const float* __restrict__ w1r, const float* __restrict__ b1r,
    const float* __restrict__ w1i, const float* __restrict__ b1i,
    bf16* __restrict__ out)
{
    int idx = blockIdx.x * 256 + threadIdx.x;      // b*4096 + m*64 + n
    int b = idx >> 12, p = idx & 4095;
    int m = p >> 6, n = p & 63;

    float v[2][9];
    #pragma unroll
    for (int dy = 0; dy < 3; ++dy)
        #pragma unroll
        for (int dx = 0; dx < 3; ++dx) {
            int yy = m + dy - 1, xx = n + dx - 1;
            bool ok = (yy >= 0 && yy < 64 && xx >= 0 && xx < 64);
            int base = ((b * 64 + (ok ? yy : 0)) * 64 + (ok ? xx : 0)) * 2;
            v[0][dy*3+dx] = ok ? x[base]     : 0.f;
            v[1][dy*3+dx] = ok ? x[base + 1] : 0.f;
        }

    float o1[64];
    #pragma unroll
    for (int o = 0; o < 32; ++o) {
        float cr = b1r[o], ci = b1i[o];
        #pragma unroll
        for (int c = 0; c < 2; ++c)
            #pragma unroll
            for (int k = 0; k < 9; ++k) {
                cr = fmaf(v[c][k], w1r[(o*2+c)*9 + k], cr);
                ci = fmaf(v[c][k], w1i[(o*2+c)*9 + k], ci);
            }
        o1[o]      = cr - ci;
        o1[32 + o] = cr + ci;
    }
    bf16* ob = out + (size_t)idx * 64;
    #pragma unroll
    for (int grp = 0; grp < 8; ++grp) {
        short8 pk;
        #pragma unroll
        for (int k = 0; k < 8; ++k) pk[k] = f2bf(o1[grp*8 + k]);
        *(short8*)(ob + grp * 8) = pk;
    }
}

// ---------------------------------------------------------------------------
// Per-channel sum/sumsq over NHWC bf16, vectorized x8. C8 = C/8.
// ---------------------------------------------------------------------------
template<int C8>
__global__ __launch_bounds__(256) void statsv_k(
    const bf16* __restrict__ t, float* __restrict__ stats, int iters)
{
    const int C = C8 * 8;
    __shared__ float ls[2 * C];
    const int tid = threadIdx.x;
    const int cg = tid & (C8 - 1), pg = tid / C8;
    const int NG = 256 / C8;
    for (int u = tid; u < 2 * C; u += 256) ls[u] = 0.f;
    __syncthreads();
    float s8[8] = {0,0,0,0,0,0,0,0}, q8[8] = {0,0,0,0,0,0,0,0};
    size_t base = (size_t)blockIdx.x * NG * iters + pg;
    for (int i = 0; i < iters; ++i) {
        size_t pp = base + (size_t)i * NG;
        short8 r = *(const short8*)(t + pp * C + cg * 8);
        #pragma unroll
        for (int k = 0; k < 8; ++k) { float v = bf2f(r[k]); s8[k] += v; q8[k] += v * v; }
    }
    #pragma unroll
    for (int k = 0; k < 8; ++k) {
        atomicAdd(&ls[cg*8 + k], s8[k]);
        atomicAdd(&ls[C + cg*8 + k], q8[k]);
    }
    __syncthreads();
    for (int u = tid; u < C; u += 256) {
        atomicAdd(&stats[u], ls[u]);
        atomicAdd(&stats[C + u], ls[C + u]);
    }
}

__global__ void bnparam_k(const float* __restrict__ stats,
                          const float* __restrict__ g, const float* __restrict__ be,
                          float* __restrict__ sc, int C)
{
    int c = threadIdx.x;
    if (c >= C) return;
    const float invN = 1.f / (128.f * 4096.f);
    float mean  = stats[c] * invN;
    float var   = stats[C + c] * invN - mean * mean;
    float scale = g[c] * rsqrtf(var + 1e-5f);
    sc[c]     = scale;
    sc[C + c] = be[c] - mean * scale;
}

// ---------------------------------------------------------------------------
// Stage NROWS input rows [row0, row0+NROWS) x 64 channels [cbase, cbase+64)
// into LDS as post-BN+relu bf16, 66-wide (zero-padded), XOR-swizzled.
// LDS byte: ((r*66+sx)*64 + c)*2 ^ ((sx&7)<<4)
// ---------------------------------------------------------------------------
template<int NROWS>
DEV void stage_act(char* actl, const bf16* __restrict__ src, const float* __restrict__ sc,
                   int Cfull, int cbase, int b, int row0, int tid)
{
    for (int u = tid; u < NROWS * 66 * 8; u += 256) {
        int r = u / (66 * 8); int rem = u - r * (66 * 8);
        int sx = rem >> 3, cg = rem & 7;
        int srow = row0 + r, gx = sx - 1;
        short8 pk = {0,0,0,0,0,0,0,0};
        if (srow >= 0 && srow < 64 && gx >= 0 && gx < 64) {
            short8 raw = *(const short8*)(src + ((size_t)(b*4096 + srow*64 + gx)) * Cfull + cbase + cg*8);
            #pragma unroll
            for (int k = 0; k < 8; ++k) {
                int c = cbase + cg*8 + k;
                float v = fmaxf(fmaf(bf2f(raw[k]), sc[c], sc[Cfull + c]), 0.f);
                pk[k] = f2bf(v);
            }
        }
        int off = (((r*66 + sx) * 64) + cg*8) * 2;
        off ^= ((sx & 7) << 4);
        *(short8*)(actl + off) = pk;
    }
}

// ---------------------------------------------------------------------------
// conv2: 64ch -> 128ch MFMA. Block: 2 rows x 128n, 4 waves (2m x 2n),
// wave = 1 row (64px) x 64n. K = 576, 18 steps. Stores t2 raw NHWC bf16.
// ---------------------------------------------------------------------------
__global__ __launch_bounds__(256) void conv2_mfma_k(
    const bf16* __restrict__ t1, const bf16* __restrict__ wf,
    const float* __restrict__ bfold, const float* __restrict__ sc,
    bf16* __restrict__ t2)
{
    __shared__ char lds[33792 + 16384];
    char* actl = lds; char* Bl = lds + 33792;
    const int b = blockIdx.y, y0 = blockIdx.x * 2;
    const int tid = threadIdx.x, l = tid & 63, w = tid >> 6;
    const int wm = w >> 1, wn = w & 1, li = l & 15, g = l >> 4;

    stage_act<4>(actl, t1, sc, 64, 0, b, y0 - 1, tid);

    float bias[4];
    #pragma unroll
    for (int nf = 0; nf < 4; ++nf) bias[nf] = bfold[wn*64 + nf*16 + li];
    f32x4 acc[4][4];
    #pragma unroll
    for (int mf = 0; mf < 4; ++mf)
        #pragma unroll
        for (int nf = 0; nf < 4; ++nf)
            acc[mf][nf] = f32x4{bias[nf], bias[nf], bias[nf], bias[nf]};

    int swz[3];
    #pragma unroll
    for (int dx = 0; dx < 3; ++dx) swz[dx] = ((li + dx) & 7) << 4;
    int bboff[4][2];
    #pragma unroll
    for (int nf = 0; nf < 4; ++nf) {
        int gg = wn*4 + nf;
        bboff[nf][0] = ((gg*2 + 0)*64 + l)*16;
        bboff[nf][1] = ((gg*2 + 1)*64 + l)*16;
    }

    short8 breg[4];
    #pragma unroll
    for (int i = 0; i < 4; ++i) breg[i] = *(const short8*)(wf + (size_t)(tid + i*256)*8);

    for (int s = 0; s < 18; ++s) {
        __syncthreads();
        #pragma unroll
        for (int i = 0; i < 4; ++i) *(short8*)(Bl + (tid + i*256)*16) = breg[i];
        if (s + 1 < 18) {
            #pragma unroll
            for (int i = 0; i < 4; ++i)
                breg[i] = *(const short8*)(wf + (size_t)(s+1)*8192 + (size_t)(tid + i*256)*8);
        }
        __syncthreads();
        int tap = s >> 1, kc = s & 1;
        int dy = (tap * 11) >> 5, dx = tap - dy * 3;
        int r = wm + dy;
        short8 a[4];
        #pragma unroll
        for (int mf = 0; mf < 4; ++mf) {
            int sx = mf*16 + li + dx;
            int off = (((r*66 + sx)*64) + kc*32 + g*8)*2 ^ swz[dx];
            a[mf] = *(const short8*)(actl + off);
        }
        #pragma unroll
        for (int nf = 0; nf < 4; ++nf) {
            short8 blo = *(const short8*)(Bl + bboff[nf][1]);
            short8 bhi = *(const short8*)(Bl + bboff[nf][0]);
            #pragma unroll
            for (int mf = 0; mf < 4; ++mf) {
                acc[mf][nf] = __builtin_amdgcn_mfma_f32_16x16x32_bf16(a[mf], blo, acc[mf][nf], 0, 0, 0);
                acc[mf][nf] = __builtin_amdgcn_mfma_f32_16x16x32_bf16(a[mf], bhi, acc[mf][nf], 0, 0, 0);
            }
        }
    }
    size_t base = (size_t)b * 4096 + (size_t)(y0 + wm) * 64;
    #pragma unroll
    for (int mf = 0; mf < 4; ++mf)
        #pragma unroll
        for (int nf = 0; nf < 4; ++nf) {
            int n = wn*64 + nf*16 + li;
            #pragma unroll
            for (int reg = 0; reg < 4; ++reg) {
                int xx = mf*16 + g*4 + reg;
                t2[(base + xx)*128 + n] = __float2bfloat16(acc[mf][nf][reg]);
            }
        }
}

// ---------------------------------------------------------------------------
// conv3 pass1: 128ch -> 256ch, stats only (no store). Block: 1 row x 128n
// (nhalf grid dim), 4 waves (wave = 64px x 32n). K-halved act staging.
// ---------------------------------------------------------------------------
__global__ __launch_bounds__(256) void conv3_pass1_k(
    const bf16* __restrict__ t2, const bf16* __restrict__ wf,
    const float* __restrict__ bfold, const float* __restrict__ sc,
    float* __restrict__ stats)
{
    __shared__ char lds[25344 + 16384 + 1024];
    char* actl = lds; char* Bl = lds + 25344;
    float* lst = (float*)(lds + 25344 + 16384);
    const int yy = blockIdx.x, b = blockIdx.y, nhalf = blockIdx.z;
    const int tid = threadIdx.x, l = tid & 63, wn = tid >> 6;
    const int li = l & 15, g = l >> 4;

    if (tid < 256) lst[tid] = 0.f;

    float bias[2];
    #pragma unroll
    for (int nf = 0; nf < 2; ++nf) bias[nf] = bfold[nhalf*128 + wn*32 + nf*16 + li];
    f32x4 acc[4][2];
    #pragma unroll
    for (int mf = 0; mf < 4; ++mf)
        #pragma unroll
        for (int nf = 0; nf < 2; ++nf)
            acc[mf][nf] = f32x4{bias[nf], bias[nf], bias[nf], bias[nf]};

    int swz[3];
    #pragma unroll
    for (int dx = 0; dx < 3; ++dx) swz[dx] = ((li + dx) & 7) << 4;
    int bboff[2][2];
    #pragma unroll
    for (int nf = 0; nf < 2; ++nf) {
        int gg = wn*2 + nf;
        bboff[nf][0] = ((gg*2 + 0)*64 + l)*16;
        bboff[nf][1] = ((gg*2 + 1)*64 + l)*16;
    }

    // ss -> weight slice element offset
    auto wsof = [&](int ss, int i) -> size_t {
        int ch = ss >= 18 ? 1 : 0;
        int t18 = ss - ch*18;
        int tap = t18 >> 1, kcl = t18 & 1;
        int wsi = tap*4 + ch*2 + kcl;
        return (size_t)(wsi*16 + nhalf*8)*1024 + (size_t)(tid + i*256)*8;
    };
    short8 breg[4];
    #pragma unroll
    for (int i = 0; i < 4; ++i) breg[i] = *(const short8*)(wf + wsof(0, i));

    for (int ss = 0; ss < 36; ++ss) {
        int chalf = ss >= 18 ? 1 : 0;
        if (ss == 0 || ss == 18) {
            __syncthreads();
            stage_act<3>(actl, t2, sc, 128, chalf*64, b, yy - 1, tid);
        }
        __syncthreads();
        #pragma unroll
        for (int i = 0; i < 4; ++i) *(short8*)(Bl + (tid + i*256)*16) = breg[i];
        if (ss + 1 < 36) {
            #pragma unroll
            for (int i = 0; i < 4; ++i) breg[i] = *(const short8*)(wf + wsof(ss + 1, i));
        }
        __syncthreads();
        int t18 = ss - chalf*18;
        int tap = t18 >> 1, kcl = t18 & 1;
        int dy = (tap * 11) >> 5, dx = tap - dy * 3;
        short8 a[4];
        #pragma unroll
        for (int mf = 0; mf < 4; ++mf) {
            int sx = mf*16 + li + dx;
            int off = (((dy*66 + sx)*64) + kcl*32 + g*8)*2 ^ swz[dx];
            a[mf] = *(const short8*)(actl + off);
        }
        #pragma unroll
        for (int nf = 0; nf < 2; ++nf) {
            short8 blo = *(const short8*)(Bl + bboff[nf][1]);
            short8 bhi = *(const short8*)(Bl + bboff[nf][0]);
            #pragma unroll
            for (int mf = 0; mf < 4; ++mf) {
                acc[mf][nf] = __builtin_amdgcn_mfma_f32_16x16x32_bf16(a[mf], blo, acc[mf][nf], 0, 0, 0);
                acc[mf][nf] = __builtin_amdgcn_mfma_f32_16x16x32_bf16(a[mf], bhi, acc[mf][nf], 0, 0, 0);
            }
        }
    }
    // stats epilogue
    #pragma unroll
    for (int nf = 0; nf < 2; ++nf) {
        float s = 0.f, q = 0.f;
        #pragma unroll
        for (int mf = 0; mf < 4; ++mf)
            #pragma unroll
            for (int reg = 0; reg < 4; ++reg) {
                float v = acc[mf][nf][reg];
                s += v; q += v * v;
            }
        s += __shfl_xor(s, 16); s += __shfl_xor(s, 32);
        q += __shfl_xor(q, 16); q += __shfl_xor(q, 32);
        if (l < 16) {
            int n = wn*32 + nf*16 + l;
            atomicAdd(&lst[n], s);
            atomicAdd(&lst[128 + n], q);
        }
    }
    __syncthreads();
    if (tid < 128) {
        atomicAdd(&stats[nhalf*128 + tid], lst[tid]);
        atomicAdd(&stats[256 + nhalf*128 + tid], lst[128 + tid]);
    }
}

// ---------------------------------------------------------------------------
// conv3 pass2: recompute conv3 + BN3 + relu + pool. Block = (32ch-chunk, b),
// 4 waves (one row each of a 4-row y-iter), 16 y-iters. pv accumulated in
// LDS; pu written per-iter; ps reduced at end. t3 never stored.
// ---------------------------------------------------------------------------
__global__ __launch_bounds__(256) void conv3_pass2_k(
    const bf16* __restrict__ t2, const bf16* __restrict__ wf,
    const float* __restrict__ bfold, const float* __restrict__ sc2,
    const float* __restrict__ sc3,
    float* __restrict__ pu, float* __restrict__ pv, float* __restrict__ ps)
{
    __shared__ char lds[50688 + 4096 + 8192];
    char* actl = lds; char* Bl = lds + 50688;
    float* pvl = (float*)(lds + 50688 + 4096);
    const int nc = blockIdx.x, b = blockIdx.y;
    const int tid = threadIdx.x, l = tid & 63, wm = tid >> 6;
    const int li = l & 15, g = l >> 4;

    for (int u = tid; u < 2048; u += 256) pvl[u] = 0.f;

    float bias[2], scale3[2], shift3[2];
    #pragma unroll
    for (int nf = 0; nf < 2; ++nf) {
        int n = nc*32 + nf*16 + li;
        bias[nf] = bfold[n]; scale3[nf] = sc3[n]; shift3[nf] = sc3[256 + n];
    }
    int swz[3];
    #pragma unroll
    for (int dx = 0; dx < 3; ++dx) swz[dx] = ((li + dx) & 7) << 4;
    int bboff[2][2];
    #pragma unroll
    for (int nf = 0; nf < 2; ++nf) {
        bboff[nf][0] = ((nf*2 + 0)*64 + l)*16;
        bboff[nf][1] = ((nf*2 + 1)*64 + l)*16;
    }
    auto wsof = [&](int ss) -> size_t {
        int ch = ss >= 18 ? 1 : 0;
        int t18 = ss - ch*18;
        int tap = t18 >> 1, kcl = t18 & 1;
        int wsi = tap*4 + ch*2 + kcl;
        return (size_t)(wsi*16 + nc*2)*1024 + (size_t)tid*8;
    };
    short8 breg = *(const short8*)(wf + wsof(0));

    for (int yi = 0; yi < 16; ++yi) {
        int y0 = yi * 4;
        f32x4 acc[4][2];
        #pragma unroll
        for (int mf = 0; mf < 4; ++mf)
            #pragma unroll
            for (int nf = 0; nf < 2; ++nf)
                acc[mf][nf] = f32x4{bias[nf], bias[nf], bias[nf], bias[nf]};

        for (int ss = 0; ss < 36; ++ss) {
            int chalf = ss >= 18 ? 1 : 0;
            if (ss == 0 || ss == 18) {
                __syncthreads();
                stage_act<6>(actl, t2, sc2, 128, chalf*64, b, y0 - 1, tid);
            }
            __syncthreads();
            *(short8*)(Bl + tid*16) = breg;
            breg = *(const short8*)(wf + wsof((ss + 1) % 36));
            __syncthreads();
            int t18 = ss - chalf*18;
            int tap = t18 >> 1, kcl = t18 & 1;
            int dy = (tap * 11) >> 5, dx = tap - dy * 3;
            int r = wm + dy;
            short8 a[4];
            #pragma unroll
            for (int mf = 0; mf < 4; ++mf) {
                int sx = mf*16 + li + dx;
                int off = (((r*66 + sx)*64) + kcl*32 + g*8)*2 ^ swz[dx];
                a[mf] = *(const short8*)(actl + off);
            }
            #pragma unroll
            for (int nf = 0; nf < 2; ++nf) {
                short8 blo = *(const short8*)(Bl + bboff[nf][1]);
                short8 bhi = *(const short8*)(Bl + bboff[nf][0]);
                #pragma unroll
                for (int mf = 0; mf < 4; ++mf) {
                    acc[mf][nf] = __builtin_amdgcn_mfma_f32_16x16x32_bf16(a[mf], blo, acc[mf][nf], 0, 0, 0);
                    acc[mf][nf] = __builtin_amdgcn_mfma_f32_16x16x32_bf16(a[mf], bhi, acc[mf][nf], 0, 0, 0);
                }
            }
        }
        // epilogue: BN3 + relu, row means (pu), LDS col accumulation (pv)
        #pragma unroll
        for (int nf = 0; nf < 2; ++nf) {
            float rs = 0.f;
            #pragma unroll
            for (int mf = 0; mf < 4; ++mf)
                #pragma unroll
                for (int reg = 0; reg < 4; ++reg) {
                    float v = fmaxf(fmaf(acc[mf][nf][reg], scale3[nf], shift3[nf]), 0.f);
                    rs += v;
                    atomicAdd(&pvl[(mf*16 + g*4 + reg)*32 + nf*16 + li], v);
                }
            rs += __shfl_xor(rs, 16); rs += __shfl_xor(rs, 32);
            if (l < 16)
                pu[((size_t)b*256 + nc*32 + nf*16 + l)*64 + (y0 + wm)] = rs * (1.f/64.f);
        }
    }
    __syncthreads();
    for (int u = tid; u < 2048; u += 256) {
        int xx = u >> 5, nl = u & 31;
        pv[((size_t)b*256 + nc*32 + nl)*64 + xx] = pvl[u] * (1.f/64.f);
    }
    __syncthreads();
    if (tid < 32) {
        float ssum = 0.f;
        for (int xx = 0; xx < 64; ++xx) ssum += pvl[xx*32 + tid];
        ps[b*256 + nc*32 + tid] = ssum * (1.f/4096.f);
    }
}

// ---------------------------------------------------------------------------
// Heads + Gram-Schmidt (unchanged from passing round-2 version).
// ---------------------------------------------------------------------------
__global__ __launch_bounds__(256) void headuv_k(
    const float* __restrict__ pool, const float* __restrict__ w,
    const float* __restrict__ bias, float* __restrict__ out)
{
    int b = blockIdx.x;
    int m = threadIdx.x & 63;
    int ob4 = threadIdx.x >> 6;
    float acc[4] = { bias[ob4], bias[ob4+4], bias[ob4+8], bias[ob4+12] };
    const float* pb = pool + (size_t)b * 256 * 64 + m;
    for (int c = 0; c < 256; ++c) {
        float v = pb[c * 64];
        #pragma unroll
        for (int i = 0; i < 4; ++i)
            acc[i] = fmaf(v, w[(ob4 + i*4) * 256 + c], acc[i]);
    }
    float* op = out + (size_t)b * 16 * 64 + m;
    #pragma unroll
    for (int i = 0; i < 4; ++i)
        op[(ob4 + i*4) * 64] = fmaxf(acc[i], 0.f);
}

__global__ __launch_bounds__(64) void heads_s_k(
    const float* __restrict__ ps, const float* __restrict__ wS,
    const float* __restrict__ bS, float* __restrict__ out)
{
    int b = blockIdx.x, lane = threadIdx.x;
    float acc[8] = {0,0,0,0,0,0,0,0};
    for (int c = lane; c < 256; c += 64) {
        float v = ps[b * 256 + c];
        #pragma unroll
        for (int o = 0; o < 8; ++o) acc[o] = fmaf(v, wS[o*256 + c], acc[o]);
    }
    #pragma unroll
    for (int o = 0; o < 8; ++o) acc[o] = wave_sum(acc[o]);
    if (lane == 0) {
        #pragma unroll
        for (int o = 0; o < 8; ++o)
            out[b*8 + o] = fmaxf(acc[o] + bS[o], 0.f);
    }
}

__global__ __launch_bounds__(64) void gs_k(
    const float* __restrict__ pre, float* __restrict__ out)
{
    int b = blockIdx.x, lane = threadIdx.x;
    const float* pb = pre + (size_t)b * 16 * 64 + lane;
    float vr[8], vi[8], den[8];
    #pragma unroll
    for (int j = 0; j < 8; ++j) { vr[j] = pb[(2*j)*64]; vi[j] = pb[(2*j+1)*64]; }

    #pragma unroll
    for (int j = 0; j < 8; ++j) {
        #pragma unroll
        for (int k = 0; k < j; ++k) {
            float d = wave_sum(vr[j]*vr[k] + vi[j]*vi[k]);
            float coef = d / den[k];
            vr[j] = fmaf(-coef, vr[k], vr[j]);
            vi[j] = fmaf(-coef, vi[k], vi[j]);
        }
        float n2 = wave_sum(vr[j]*vr[j] + vi[j]*vi[j]);
        float inv = 1.f / sqrtf(n2 + 1e-8f);
        vr[j] *= inv; vi[j] *= inv;
        float nn = wave_sum(vr[j]*vr[j] + vi[j]*vi[j]);
        den[j] = nn + 1e-8f;
    }
    float* ob = out + (size_t)b * 64 * 16 + lane * 16;
    #pragma unroll
    for (int j = 0; j < 8; ++j) { ob[j*2] = vr[j]; ob[j*2+1] = vi[j]; }
}

// ---------------------------------------------------------------------------
extern "C" void kernel_launch(void* const* d_in, const int* in_sizes, int n_in,
                              void* d_out, int out_size, void* d_ws, size_t ws_size,
                              hipStream_t stream)
{
    const float* x   = (const float*)d_in[0];
    const float* w1r = (const float*)d_in[1];
    const float* b1r = (const float*)d_in[2];
    const float* w1i = (const float*)d_in[3];
    const float* b1i = (const float*)d_in[4];
    const float* g1  = (const float*)d_in[5];
    const float* be1 = (const float*)d_in[6];
    const float* w2r = (const float*)d_in[7];
    const float* b2r = (const float*)d_in[8];
    const float* w2i = (const float*)d_in[9];
    const float* b2i = (const float*)d_in[10];
    const float* g2  = (const float*)d_in[11];
    const float* be2 = (const float*)d_in[12];
    const float* w3r = (const float*)d_in[13];
    const float* b3r = (const float*)d_in[14];
    const float* w3i = (const float*)d_in[15];
    const float* b3i = (const float*)d_in[16];
    const float* g3  = (const float*)d_in[17];
    const float* be3 = (const float*)d_in[18];
    const float* wu  = (const float*)d_in[19];
    const float* bu  = (const float*)d_in[20];
    const float* wS  = (const float*)d_in[21];
    const float* bS  = (const float*)d_in[22];
    const float* wv  = (const float*)d_in[23];
    const float* bv  = (const float*)d_in[24];
    float* out = (float*)d_out;

    char* ws = (char*)d_ws;
    // Layout (total = 219,290,624 B == round-2 proven-safe footprint):
    bf16*  t2     = (bf16*)(ws + 0);                       // 134,217,728
    bf16*  t1     = (bf16*)(ws + 134217728);               //  67,108,864
    bf16*  wfrag3 = (bf16*)(ws + 134217728);               // overlays t1 (dead after conv2)
    float* pu     = (float*)(ws + 201326592);              //   8,388,608
    float* pv     = (float*)(ws + 209715200);              //   8,388,608
    float* ps     = (float*)(ws + 218103808);              //     131,072
    // X region: wfrag2 + bfolds overlay upre (upre written only after pass2)
    bf16*  wfrag2 = (bf16*)(ws + 218234880);               //     294,912
    float* bfold2 = (float*)(ws + 218234880 + 294912);     //         512
    float* bfold3 = (float*)(ws + 218234880 + 295424);     //       1,024
    float* upre   = (float*)(ws + 218234880);              //     524,288
    float* vpre   = (float*)(ws + 218759168);              //     524,288
    float* stats  = (float*)(ws + 219283456);              //       3,584
    float* scsh   = (float*)(ws + 219287040);              //       3,584
    float* stats1 = stats, *stats2 = stats + 128, *stats3 = stats + 384;
    float* sc1 = scsh, *sc2 = scsh + 128, *sc3 = scsh + 384;

    hipMemsetAsync(stats, 0, 896 * 4, stream);

    // weight prep (conv2 now; conv3 after conv2 frees t1 region)
    prep_w_k<<<576, 256, 0, stream>>>(w2r, w2i, b2r, b2i, wfrag2, bfold2, 64, 64);

    // layer 1
    conv1_k<<<2048, 256, 0, stream>>>(x, w1r, b1r, w1i, b1i, t1);
    statsv_k<8><<<1024, 256, 0, stream>>>(t1, stats1, 16);
    bnparam_k<<<1, 64, 0, stream>>>(stats1, g1, be1, sc1, 64);

    // layer 2 (BN1+relu folded into staging)
    conv2_mfma_k<<<dim3(32, 128), 256, 0, stream>>>(t1, wfrag2, bfold2, sc1, t2);
    statsv_k<16><<<1024, 256, 0, stream>>>(t2, stats2, 32);
    bnparam_k<<<1, 128, 0, stream>>>(stats2, g2, be2, sc2, 128);

    // layer 3: prep weights into dead t1 region, then two passes, no t3.
    prep_w_k<<<2304, 256, 0, stream>>>(w3r, w3i, b3r, b3i, wfrag3, bfold3, 128, 128);
    conv3_pass1_k<<<dim3(64, 128, 2), 256, 0, stream>>>(t2, wfrag3, bfold3, sc2, stats3);
    bnparam_k<<<1, 256, 0, stream>>>(stats3, g3, be3, sc3, 256);
    conv3_pass2_k<<<dim3(8, 128), 256, 0, stream>>>(t2, wfrag3, bfold3, sc2, sc3, pu, pv, ps);

    // heads
    headuv_k<<<128, 256, 0, stream>>>(pu, wu, bu, upre);
    headuv_k<<<128, 256, 0, stream>>>(pv, wv, bv, vpre);
    heads_s_k<<<128, 64, 0, stream>>>(ps, wS, bS, out + 131072);

    // gram-schmidt
    gs_k<<<128, 64, 0, stream>>>(upre, out);
    gs_k<<<128, 64, 0, stream>>>(vpre, out + 132096);
}

// Round 4
// 1030.062 us; speedup vs baseline: 13.4367x; 2.4789x over previous
//
#include <hip/hip_runtime.h>
#include <hip/hip_bf16.h>
#include <hip/hip_fp16.h>

typedef __hip_bfloat16 bf16;
typedef __attribute__((ext_vector_type(8))) short short8;
typedef __attribute__((ext_vector_type(4))) float f32x4;

#define DEV __device__ __forceinline__

DEV float bf2f(short s) {
    unsigned int u = ((unsigned int)(unsigned short)s) << 16;
    float f; __builtin_memcpy(&f, &u, 4); return f;
}
DEV short f2bf(float f) {
    __hip_bfloat16 h = __float2bfloat16(f);
    short s; __builtin_memcpy(&s, &h, 2); return s;
}

DEV float wave_sum(float v) {
    #pragma unroll
    for (int m = 1; m < 64; m <<= 1) v += __shfl_xor(v, m);
    return v;
}

// ---------------------------------------------------------------------------
// Weight prep: fold complex conv (wA = wr-wi for n<COUT, wB = wr+wi), split
// hi/lo bf16, pack into MFMA fragment order:
//   flat = (((s*NG+gg)*2+ver)*64+lane)*8+j,  s = tap*KC+kc,
//   n = gg*16+(lane&15), cin = kc*32+(lane>>4)*8+j.
// Conv biases are dropped entirely: they cancel exactly through batchnorm.
// ---------------------------------------------------------------------------
__global__ __launch_bounds__(256) void prep_w_k(
    const float* __restrict__ wr, const float* __restrict__ wi,
    bf16* __restrict__ wf, int CIN, int COUT)
{
    int idx = blockIdx.x * 256 + threadIdx.x;
    int KC = CIN >> 5, NG = (2 * COUT) >> 4;
    int total = 9 * KC * NG * 1024;
    if (idx >= total) return;
    int j = idx & 7, lane = (idx >> 3) & 63, ver = (idx >> 9) & 1;
    int t10 = idx >> 10;
    int gg = t10 % NG, s = t10 / NG;
    int kc = s % KC, tap = s / KC;
    int n = gg * 16 + (lane & 15);
    int cin = kc * 32 + (lane >> 4) * 8 + j;
    int o = n < COUT ? n : n - COUT;
    float sgn = n < COUT ? -1.f : 1.f;
    float wv = wr[(o * CIN + cin) * 9 + tap] + sgn * wi[(o * CIN + cin) * 9 + tap];
    __hip_bfloat16 hi = __float2bfloat16(wv);
    float rem = wv - __bfloat162float(hi);
    wf[idx] = ver ? __float2bfloat16(rem) : hi;
}

// ---------------------------------------------------------------------------
// conv1: 2 -> 64 channels, fp32 VALU, NHWC bf16 output. No bias (BN removes).
// ---------------------------------------------------------------------------
__global__ __launch_bounds__(256) void conv1_k(
    const float* __restrict__ x,
    const float* __restrict__ w1r, const float* __restrict__ w1i,
    bf16* __restrict__ out)
{
    int idx = blockIdx.x * 256 + threadIdx.x;      // b*4096 + m*64 + n
    int b = idx >> 12, p = idx & 4095;
    int m = p >> 6, n = p & 63;

    float v[2][9];
    #pragma unroll
    for (int dy = 0; dy < 3; ++dy)
        #pragma unroll
        for (int dx = 0; dx < 3; ++dx) {
            int yy = m + dy - 1, xx = n + dx - 1;
            bool ok = (yy >= 0 && yy < 64 && xx >= 0 && xx < 64);
            int base = ((b * 64 + (ok ? yy : 0)) * 64 + (ok ? xx : 0)) * 2;
            v[0][dy*3+dx] = ok ? x[base]     : 0.f;
            v[1][dy*3+dx] = ok ? x[base + 1] : 0.f;
        }

    float o1[64];
    #pragma unroll
    for (int o = 0; o < 32; ++o) {
        float cr = 0.f, ci = 0.f;
        #pragma unroll
        for (int c = 0; c < 2; ++c)
            #pragma unroll
            for (int k = 0; k < 9; ++k) {
                cr = fmaf(v[c][k], w1r[(o*2+c)*9 + k], cr);
                ci = fmaf(v[c][k], w1i[(o*2+c)*9 + k], ci);
            }
        o1[o]      = cr - ci;
        o1[32 + o] = cr + ci;
    }
    bf16* ob = out + (size_t)idx * 64;
    #pragma unroll
    for (int grp = 0; grp < 8; ++grp) {
        short8 pk;
        #pragma unroll
        for (int k = 0; k < 8; ++k) pk[k] = f2bf(o1[grp*8 + k]);
        *(short8*)(ob + grp * 8) = pk;
    }
}

// ---------------------------------------------------------------------------
// Per-channel sum/sumsq over NHWC bf16, vectorized x8. C8 = C/8.
// ---------------------------------------------------------------------------
template<int C8>
__global__ __launch_bounds__(256) void statsv_k(
    const bf16* __restrict__ t, float* __restrict__ stats, int iters)
{
    const int C = C8 * 8;
    __shared__ float ls[2 * C];
    const int tid = threadIdx.x;
    const int cg = tid & (C8 - 1), pg = tid / C8;
    const int NG = 256 / C8;
    for (int u = tid; u < 2 * C; u += 256) ls[u] = 0.f;
    __syncthreads();
    float s8[8] = {0,0,0,0,0,0,0,0}, q8[8] = {0,0,0,0,0,0,0,0};
    size_t base = (size_t)blockIdx.x * NG * iters + pg;
    for (int i = 0; i < iters; ++i) {
        size_t pp = base + (size_t)i * NG;
        short8 r = *(const short8*)(t + pp * C + cg * 8);
        #pragma unroll
        for (int k = 0; k < 8; ++k) { float v = bf2f(r[k]); s8[k] += v; q8[k] += v * v; }
    }
    #pragma unroll
    for (int k = 0; k < 8; ++k) {
        atomicAdd(&ls[cg*8 + k], s8[k]);
        atomicAdd(&ls[C + cg*8 + k], q8[k]);
    }
    __syncthreads();
    for (int u = tid; u < C; u += 256) {
        atomicAdd(&stats[u], ls[u]);
        atomicAdd(&stats[C + u], ls[C + u]);
    }
}

__global__ void bnparam_k(const float* __restrict__ stats,
                          const float* __restrict__ g, const float* __restrict__ be,
                          float* __restrict__ sc, int C)
{
    int c = threadIdx.x;
    if (c >= C) return;
    const float invN = 1.f / (128.f * 4096.f);
    float mean  = stats[c] * invN;
    float var   = stats[C + c] * invN - mean * mean;
    float scale = g[c] * rsqrtf(var + 1e-5f);
    sc[c]     = scale;
    sc[C + c] = be[c] - mean * scale;
}

// ---------------------------------------------------------------------------
// Unified MFMA conv: CIN in-ch (BN_in+relu fused at staging), 64 out-ch per
// block. Block = 4 rows x 64 n, 4 waves (wave = 1 row x 64 n), acc[4][4].
// K staged in 32-ch quarters (act LDS 25.3KB, swizzled). Hi/lo split weights.
// Epilogue: per-channel sum/sumsq -> atomics; store bf16 (stride) or fp16.
// grid: (16 y-blocks, 128 b, nz). n0_eff = n0 + blockIdx.z*64.
// ---------------------------------------------------------------------------
template<int CIN, bool FP16OUT>
__global__ __launch_bounds__(256) void conv_mfma_k(
    const bf16* __restrict__ in, const bf16* __restrict__ wf,
    const float* __restrict__ scin,
    bf16* __restrict__ outb, __half* __restrict__ outh,
    float* __restrict__ stats,
    int n0, int ngtot, int statsC, int ostride)
{
    constexpr int KQ = CIN / 32;
    __shared__ char actl[6*66*32*2];         // 25344
    __shared__ char Bl[8192];
    __shared__ float lsts[4][64], lstq[4][64];
    const int b = blockIdx.y, y0 = blockIdx.x * 4;
    const int n0e = n0 + blockIdx.z * 64;
    const int tid = threadIdx.x, l = tid & 63, w = tid >> 6;
    const int li = l & 15, g = l >> 4;

    f32x4 acc[4][4];
    #pragma unroll
    for (int mf = 0; mf < 4; ++mf)
        #pragma unroll
        for (int nf = 0; nf < 4; ++nf)
            acc[mf][nf] = f32x4{0.f, 0.f, 0.f, 0.f};

    int swz[3];
    #pragma unroll
    for (int dx = 0; dx < 3; ++dx) swz[dx] = ((li + dx) & 7) << 4;

    // B fragment global element offset for step st, half i
    auto wbase = [&](int st, int i) -> size_t {
        int kq = st / 9, tap = st % 9;
        int s = tap * KQ + kq;
        int u = tid + i * 256;                 // [0,512)
        int gg2 = u >> 7, ver = (u >> 6) & 1, lane = u & 63;
        return (((size_t)(s * ngtot + (n0e >> 4) + gg2) * 2 + ver) * 64 + lane) * 8;
    };
    short8 breg[2];
    breg[0] = *(const short8*)(wf + wbase(0, 0));
    breg[1] = *(const short8*)(wf + wbase(0, 1));

    const int NSTEP = KQ * 9;
    for (int st = 0; st < NSTEP; ++st) {
        int kq = st / 9, tap = st % 9;
        if (tap == 0) {
            __syncthreads();
            // stage act quarter kq: rows y0-1..y0+4, ch [kq*32, kq*32+32)
            for (int u = tid; u < 6*66*4; u += 256) {
                int r = u / 264, rem = u - r * 264;
                int sx = rem >> 2, cg = rem & 3;
                int srow = y0 - 1 + r, gx = sx - 1;
                short8 pk = {0,0,0,0,0,0,0,0};
                if (srow >= 0 && srow < 64 && gx >= 0 && gx < 64) {
                    short8 raw = *(const short8*)(in +
                        ((size_t)(b*4096 + srow*64 + gx)) * CIN + kq*32 + cg*8);
                    #pragma unroll
                    for (int k = 0; k < 8; ++k) {
                        int c = kq*32 + cg*8 + k;
                        float v = fmaxf(fmaf(bf2f(raw[k]), scin[c], scin[CIN + c]), 0.f);
                        pk[k] = f2bf(v);
                    }
                }
                int off = ((r*66 + sx)*32 + cg*8)*2 ^ ((sx & 7) << 4);
                *(short8*)(actl + off) = pk;
            }
        }
        __syncthreads();
        *(short8*)(Bl + tid*16)        = breg[0];
        *(short8*)(Bl + (tid+256)*16)  = breg[1];
        if (st + 1 < NSTEP) {
            breg[0] = *(const short8*)(wf + wbase(st+1, 0));
            breg[1] = *(const short8*)(wf + wbase(st+1, 1));
        }
        __syncthreads();
        int dy = (tap * 11) >> 5, dx = tap - dy * 3;
        int r = w + dy;
        short8 a[4];
        #pragma unroll
        for (int mf = 0; mf < 4; ++mf) {
            int sx = mf*16 + li + dx;
            a[mf] = *(const short8*)(actl + ((((r*66 + sx)*32) + g*8)*2 ^ swz[dx]));
        }
        #pragma unroll
        for (int nf = 0; nf < 4; ++nf) {
            short8 blo = *(const short8*)(Bl + ((nf*2 + 1)*64 + l)*16);
            short8 bhi = *(const short8*)(Bl + ((nf*2 + 0)*64 + l)*16);
            #pragma unroll
            for (int mf = 0; mf < 4; ++mf) {
                acc[mf][nf] = __builtin_amdgcn_mfma_f32_16x16x32_bf16(a[mf], blo, acc[mf][nf], 0, 0, 0);
                acc[mf][nf] = __builtin_amdgcn_mfma_f32_16x16x32_bf16(a[mf], bhi, acc[mf][nf], 0, 0, 0);
            }
        }
    }

    // ---- stats epilogue (pre-BN sums): reduce over px, accumulate global
    #pragma unroll
    for (int nf = 0; nf < 4; ++nf) {
        float s = 0.f, q = 0.f;
        #pragma unroll
        for (int mf = 0; mf < 4; ++mf)
            #pragma unroll
            for (int reg = 0; reg < 4; ++reg) {
                float v = acc[mf][nf][reg];
                s += v; q += v * v;
            }
        s += __shfl_xor(s, 16); s += __shfl_xor(s, 32);
        q += __shfl_xor(q, 16); q += __shfl_xor(q, 32);
        if (l < 16) { lsts[w][nf*16 + l] = s; lstq[w][nf*16 + l] = q; }
    }
    __syncthreads();
    if (tid < 64) {
        int sb = FP16OUT ? 0 : n0e;
        float s = lsts[0][tid] + lsts[1][tid] + lsts[2][tid] + lsts[3][tid];
        float q = lstq[0][tid] + lstq[1][tid] + lstq[2][tid] + lstq[3][tid];
        atomicAdd(&stats[sb + tid], s);
        atomicAdd(&stats[statsC + sb + tid], q);
    }

    // ---- store
    size_t rowbase = (size_t)b * 4096 + (size_t)(y0 + w) * 64;
    const int obase = FP16OUT ? 0 : n0e;
    #pragma unroll
    for (int mf = 0; mf < 4; ++mf)
        #pragma unroll
        for (int nf = 0; nf < 4; ++nf) {
            int n = obase + nf*16 + li;
            #pragma unroll
            for (int reg = 0; reg < 4; ++reg) {
                int xx = mf*16 + g*4 + reg;
                if (FP16OUT)
                    outh[(rowbase + xx) * ostride + n] = __float2half(acc[mf][nf][reg]);
                else
                    outb[(rowbase + xx) * ostride + n] = __float2bfloat16(acc[mf][nf][reg]);
            }
        }
}

// ---------------------------------------------------------------------------
// Pool chunk: BN+relu on fp16 chunk (64 ch), produce pu (row means, direct
// write) and pv (col means, atomicAdd across 2 y-half blocks). grid (128,2).
// ---------------------------------------------------------------------------
__global__ __launch_bounds__(256) void pool_k(
    const __half* __restrict__ t3c, const float* __restrict__ sc3c,
    float* __restrict__ pu, float* __restrict__ pv, int ncb)
{
    const int b = blockIdx.x, yh = blockIdx.y;
    const int t = threadIdx.x, cg = t & 7, xp = t >> 3;
    const int w = t >> 6, lane = t & 63;
    __shared__ float rq[4][16][64];
    float scl[8], shf[8];
    #pragma unroll
    for (int k = 0; k < 8; ++k) { scl[k] = sc3c[cg*8 + k]; shf[k] = sc3c[64 + cg*8 + k]; }
    float colacc[2][8];
    #pragma unroll
    for (int xi = 0; xi < 2; ++xi)
        #pragma unroll
        for (int k = 0; k < 8; ++k) colacc[xi][k] = 0.f;

    for (int yb = 0; yb < 2; ++yb) {
        for (int yy = 0; yy < 16; ++yy) {
            int y = yh*32 + yb*16 + yy;
            float rc[8];
            #pragma unroll
            for (int xi = 0; xi < 2; ++xi) {
                int xx = xp*2 + xi;
                short8 raw = *(const short8*)(t3c +
                    ((size_t)(b*4096 + y*64 + xx)) * 64 + cg*8);
                #pragma unroll
                for (int k = 0; k < 8; ++k) {
                    __half hv; short s = raw[k]; __builtin_memcpy(&hv, &s, 2);
                    float v = fmaxf(fmaf(__half2float(hv), scl[k], shf[k]), 0.f);
                    colacc[xi][k] += v;
                    rc[k] = xi ? (rc[k] + v) : v;
                }
            }
            #pragma unroll
            for (int k = 0; k < 8; ++k) {
                rc[k] += __shfl_xor(rc[k], 8);
                rc[k] += __shfl_xor(rc[k], 16);
                rc[k] += __shfl_xor(rc[k], 32);
            }
            if (lane < 8) {
                #pragma unroll
                for (int k = 0; k < 8; ++k) rq[w][yy][lane*8 + k] = rc[k];
            }
        }
        __syncthreads();
        for (int u = t; u < 1024; u += 256) {
            int yy = u >> 6, c = u & 63;
            float v = rq[0][yy][c] + rq[1][yy][c] + rq[2][yy][c] + rq[3][yy][c];
            pu[((size_t)b*256 + ncb + c)*64 + (yh*32 + yb*16 + yy)] = v * (1.f/64.f);
        }
        __syncthreads();
    }
    #pragma unroll
    for (int xi = 0; xi < 2; ++xi)
        #pragma unroll
        for (int k = 0; k < 8; ++k)
            atomicAdd(&pv[((size_t)b*256 + ncb + cg*8 + k)*64 + xp*2 + xi],
                      colacc[xi][k] * (1.f/64.f));
}

// ---------------------------------------------------------------------------
// u/v head: out[b][o][m] = relu(sum_c pool[b][c][m] * w[o][c] + bias[o])
// ---------------------------------------------------------------------------
__global__ __launch_bounds__(256) void headuv_k(
    const float* __restrict__ pool, const float* __restrict__ w,
    const float* __restrict__ bias, float* __restrict__ out)
{
    int b = blockIdx.x;
    int m = threadIdx.x & 63;
    int ob4 = threadIdx.x >> 6;
    float acc[4] = { bias[ob4], bias[ob4+4], bias[ob4+8], bias[ob4+12] };
    const float* pb = pool + (size_t)b * 256 * 64 + m;
    for (int c = 0; c < 256; ++c) {
        float v = pb[c * 64];
        #pragma unroll
        for (int i = 0; i < 4; ++i)
            acc[i] = fmaf(v, w[(ob4 + i*4) * 256 + c], acc[i]);
    }
    float* op = out + (size_t)b * 16 * 64 + m;
    #pragma unroll
    for (int i = 0; i < 4; ++i)
        op[(ob4 + i*4) * 64] = fmaxf(acc[i], 0.f);
}

// s head: ps derived from pu (ps[b][c] = mean_m pu[b][c][m]); 1 wave per b.
__global__ __launch_bounds__(64) void heads_s_k(
    const float* __restrict__ pu, const float* __restrict__ wS,
    const float* __restrict__ bS, float* __restrict__ out)
{
    int b = blockIdx.x, lane = threadIdx.x;
    __shared__ float ls[256];
    for (int i = 0; i < 4; ++i) {
        const float* p = pu + ((size_t)b*256 + lane*4 + i) * 64;
        float s = 0.f;
        for (int m = 0; m < 64; ++m) s += p[m];
        ls[lane*4 + i] = s * (1.f/64.f);
    }
    __syncthreads();
    float acc[8] = {0,0,0,0,0,0,0,0};
    for (int c = lane; c < 256; c += 64) {
        float v = ls[c];
        #pragma unroll
        for (int o = 0; o < 8; ++o) acc[o] = fmaf(v, wS[o*256 + c], acc[o]);
    }
    #pragma unroll
    for (int o = 0; o < 8; ++o) acc[o] = wave_sum(acc[o]);
    if (lane == 0) {
        #pragma unroll
        for (int o = 0; o < 8; ++o)
            out[b*8 + o] = fmaxf(acc[o] + bS[o], 0.f);
    }
}

// ---------------------------------------------------------------------------
// Gram-Schmidt: one wave per batch, lane = m. pre: (B,16,64), out: (B,64,8,2)
// ---------------------------------------------------------------------------
__global__ __launch_bounds__(64) void gs_k(
    const float* __restrict__ pre, float* __restrict__ out)
{
    int b = blockIdx.x, lane = threadIdx.x;
    const float* pb = pre + (size_t)b * 16 * 64 + lane;
    float vr[8], vi[8], den[8];
    #pragma unroll
    for (int j = 0; j < 8; ++j) { vr[j] = pb[(2*j)*64]; vi[j] = pb[(2*j+1)*64]; }

    #pragma unroll
    for (int j = 0; j < 8; ++j) {
        #pragma unroll
        for (int k = 0; k < j; ++k) {
            float d = wave_sum(vr[j]*vr[k] + vi[j]*vi[k]);
            float coef = d / den[k];
            vr[j] = fmaf(-coef, vr[k], vr[j]);
            vi[j] = fmaf(-coef, vi[k], vi[j]);
        }
        float n2 = wave_sum(vr[j]*vr[j] + vi[j]*vi[j]);
        float inv = 1.f / sqrtf(n2 + 1e-8f);
        vr[j] *= inv; vi[j] *= inv;
        float nn = wave_sum(vr[j]*vr[j] + vi[j]*vi[j]);
        den[j] = nn + 1e-8f;
    }
    float* ob = out + (size_t)b * 64 * 16 + lane * 16;
    #pragma unroll
    for (int j = 0; j < 8; ++j) { ob[j*2] = vr[j]; ob[j*2+1] = vi[j]; }
}

// ---------------------------------------------------------------------------
extern "C" void kernel_launch(void* const* d_in, const int* in_sizes, int n_in,
                              void* d_out, int out_size, void* d_ws, size_t ws_size,
                              hipStream_t stream)
{
    const float* x   = (const float*)d_in[0];
    const float* w1r = (const float*)d_in[1];
    const float* w1i = (const float*)d_in[3];
    const float* g1  = (const float*)d_in[5];
    const float* be1 = (const float*)d_in[6];
    const float* w2r = (const float*)d_in[7];
    const float* w2i = (const float*)d_in[9];
    const float* g2  = (const float*)d_in[11];
    const float* be2 = (const float*)d_in[12];
    const float* w3r = (const float*)d_in[13];
    const float* w3i = (const float*)d_in[15];
    const float* g3  = (const float*)d_in[17];
    const float* be3 = (const float*)d_in[18];
    const float* wu  = (const float*)d_in[19];
    const float* bu  = (const float*)d_in[20];
    const float* wS  = (const float*)d_in[21];
    const float* bS  = (const float*)d_in[22];
    const float* wv  = (const float*)d_in[23];
    const float* bv  = (const float*)d_in[24];
    float* out = (float*)d_out;

    char* ws = (char*)d_ws;
    // Layout, total 219,290,624 B == round-2/3 proven-safe footprint.
    bf16*   t2     = (bf16*)  (ws + 0);            // 134,217,728
    bf16*   t1     = (bf16*)  (ws + 134217728);    //  67,108,864 (dead after conv2)
    __half* t3c    = (__half*)(ws + 134217728);    //  67,108,864 (overlays t1)
    float*  upre   = (float*) (ws + 134217728);    // 524,288 (after pools; t3c dead)
    float*  vpre   = (float*) (ws + 134742016);    // 524,288
    float*  pu     = (float*) (ws + 201326592);    //   8,388,608
    float*  pv     = (float*) (ws + 209715200);    //   8,388,608
    // wreg region: wfrag2 (294,912) then overwritten by wfrag3 (1,179,648)
    bf16*   wfrag2 = (bf16*)  (ws + 218103808);
    bf16*   wfrag3 = (bf16*)  (ws + 218103808);    // ends 219,283,456
    float*  stats  = (float*) (ws + 219283456);    // 512 floats (2048 B)
    float*  scsh   = (float*) (ws + 219285504);    // 512 floats (2048 B)
    float*  stats1 = stats,       *stats2 = stats + 128, *stats3c = stats + 384;
    float*  sc1    = scsh,        *sc2    = scsh  + 128, *sc3c    = scsh  + 384;

    hipMemsetAsync(stats, 0, 2048, stream);
    hipMemsetAsync(pv, 0, (size_t)128*256*64*4, stream);

    // ---- weight prep for conv2
    prep_w_k<<<576, 256, 0, stream>>>(w2r, w2i, wfrag2, 64, 64);

    // ---- layer 1
    conv1_k<<<2048, 256, 0, stream>>>(x, w1r, w1i, t1);
    statsv_k<8><<<1024, 256, 0, stream>>>(t1, stats1, 16);
    bnparam_k<<<1, 64, 0, stream>>>(stats1, g1, be1, sc1, 64);

    // ---- layer 2 (BN1+relu fused in staging; stats fused in epilogue)
    conv_mfma_k<64, false><<<dim3(16, 128, 2), 256, 0, stream>>>(
        t1, wfrag2, sc1, t2, (__half*)nullptr, stats2,
        /*n0=*/0, /*ngtot=*/8, /*statsC=*/128, /*ostride=*/128);
    bnparam_k<<<1, 128, 0, stream>>>(stats2, g2, be2, sc2, 128);

    // ---- layer 3: conv once, 4 chunks of 64 out-ch (t3 chunk in fp16)
    prep_w_k<<<2304, 256, 0, stream>>>(w3r, w3i, wfrag3, 128, 128);
    for (int nc = 0; nc < 4; ++nc) {
        hipMemsetAsync(stats3c, 0, 512, stream);
        conv_mfma_k<128, true><<<dim3(16, 128, 1), 256, 0, stream>>>(
            t2, wfrag3, sc2, (bf16*)nullptr, t3c, stats3c,
            /*n0=*/nc*64, /*ngtot=*/16, /*statsC=*/64, /*ostride=*/64);
        bnparam_k<<<1, 64, 0, stream>>>(stats3c, g3 + nc*64, be3 + nc*64, sc3c, 64);
        pool_k<<<dim3(128, 2), 256, 0, stream>>>(t3c, sc3c, pu, pv, nc*64);
    }

    // ---- heads
    headuv_k<<<128, 256, 0, stream>>>(pu, wu, bu, upre);
    headuv_k<<<128, 256, 0, stream>>>(pv, wv, bv, vpre);
    heads_s_k<<<128, 64, 0, stream>>>(pu, wS, bS, out + 131072);

    // ---- gram-schmidt
    gs_k<<<128, 64, 0, stream>>>(upre, out);            // u at [0, 131072)
    gs_k<<<128, 64, 0, stream>>>(vpre, out + 132096);   // v at [132096, 263168)
}

// Round 5
// 997.108 us; speedup vs baseline: 13.8808x; 1.0330x over previous
//
#include <hip/hip_runtime.h>

typedef _Float16 f16;
typedef __attribute__((ext_vector_type(8))) short short8;
typedef __attribute__((ext_vector_type(8))) _Float16 half8;
typedef __attribute__((ext_vector_type(4))) float f32x4;

#define DEV __device__ __forceinline__

DEV float h2f(short s) { f16 h; __builtin_memcpy(&h, &s, 2); return (float)h; }
DEV short f2h(float f) { f16 h = (f16)f; short s; __builtin_memcpy(&s, &h, 2); return s; }
DEV half8 s2h8(short8 s) { half8 h; __builtin_memcpy(&h, &s, 16); return h; }

DEV float wave_sum(float v) {
    #pragma unroll
    for (int m = 1; m < 64; m <<= 1) v += __shfl_xor(v, m);
    return v;
}

// ---------------------------------------------------------------------------
// Weight prep: fold complex conv (wA = wr-wi for n<COUT, wB = wr+wi), fp16,
// MFMA fragment order: flat = ((s*NG+gg)*64+lane)*8+j, s = tap*KC+kc,
// n = gg*16+(lane&15), cin = kc*32+(lane>>4)*8+j. Conv biases dropped (BN
// cancels them exactly).
// ---------------------------------------------------------------------------
__global__ __launch_bounds__(256) void prep_w_k(
    const float* __restrict__ wr, const float* __restrict__ wi,
    f16* __restrict__ wf, int CIN, int COUT)
{
    int idx = blockIdx.x * 256 + threadIdx.x;
    int KC = CIN >> 5, NG = (2 * COUT) >> 4;
    int total = 9 * KC * NG * 512;
    if (idx >= total) return;
    int j = idx & 7, lane = (idx >> 3) & 63;
    int t9 = idx >> 9;
    int gg = t9 % NG, s = t9 / NG;
    int kc = s % KC, tap = s / KC;
    int n = gg * 16 + (lane & 15);
    int cin = kc * 32 + (lane >> 4) * 8 + j;
    int o = n < COUT ? n : n - COUT;
    float sgn = n < COUT ? -1.f : 1.f;
    float wv = wr[(o * CIN + cin) * 9 + tap] + sgn * wi[(o * CIN + cin) * 9 + tap];
    wf[idx] = (f16)wv;
}

// ---------------------------------------------------------------------------
// conv1: 2 -> 64 channels, fp32 VALU, NHWC fp16 output. No bias (BN removes).
// ---------------------------------------------------------------------------
__global__ __launch_bounds__(256) void conv1_k(
    const float* __restrict__ x,
    const float* __restrict__ w1r, const float* __restrict__ w1i,
    f16* __restrict__ out)
{
    int idx = blockIdx.x * 256 + threadIdx.x;      // b*4096 + m*64 + n
    int b = idx >> 12, p = idx & 4095;
    int m = p >> 6, n = p & 63;

    float v[2][9];
    #pragma unroll
    for (int dy = 0; dy < 3; ++dy)
        #pragma unroll
        for (int dx = 0; dx < 3; ++dx) {
            int yy = m + dy - 1, xx = n + dx - 1;
            bool ok = (yy >= 0 && yy < 64 && xx >= 0 && xx < 64);
            int base = ((b * 64 + (ok ? yy : 0)) * 64 + (ok ? xx : 0)) * 2;
            v[0][dy*3+dx] = ok ? x[base]     : 0.f;
            v[1][dy*3+dx] = ok ? x[base + 1] : 0.f;
        }

    float o1[64];
    #pragma unroll
    for (int o = 0; o < 32; ++o) {
        float cr = 0.f, ci = 0.f;
        #pragma unroll
        for (int c = 0; c < 2; ++c)
            #pragma unroll
            for (int k = 0; k < 9; ++k) {
                cr = fmaf(v[c][k], w1r[(o*2+c)*9 + k], cr);
                ci = fmaf(v[c][k], w1i[(o*2+c)*9 + k], ci);
            }
        o1[o]      = cr - ci;
        o1[32 + o] = cr + ci;
    }
    f16* ob = out + (size_t)idx * 64;
    #pragma unroll
    for (int grp = 0; grp < 8; ++grp) {
        short8 pk;
        #pragma unroll
        for (int k = 0; k < 8; ++k) pk[k] = f2h(o1[grp*8 + k]);
        *(short8*)(ob + grp * 8) = pk;
    }
}

// ---------------------------------------------------------------------------
// Per-channel sum/sumsq over NHWC fp16, vectorized x8. C8 = C/8.
// ---------------------------------------------------------------------------
template<int C8>
__global__ __launch_bounds__(256) void statsv_k(
    const f16* __restrict__ t, float* __restrict__ stats, int iters)
{
    const int C = C8 * 8;
    __shared__ float ls[2 * C];
    const int tid = threadIdx.x;
    const int cg = tid & (C8 - 1), pg = tid / C8;
    const int NG = 256 / C8;
    for (int u = tid; u < 2 * C; u += 256) ls[u] = 0.f;
    __syncthreads();
    float s8[8] = {0,0,0,0,0,0,0,0}, q8[8] = {0,0,0,0,0,0,0,0};
    size_t base = (size_t)blockIdx.x * NG * iters + pg;
    for (int i = 0; i < iters; ++i) {
        size_t pp = base + (size_t)i * NG;
        short8 r = *(const short8*)(t + pp * C + cg * 8);
        #pragma unroll
        for (int k = 0; k < 8; ++k) { float v = h2f(r[k]); s8[k] += v; q8[k] += v * v; }
    }
    #pragma unroll
    for (int k = 0; k < 8; ++k) {
        atomicAdd(&ls[cg*8 + k], s8[k]);
        atomicAdd(&ls[C + cg*8 + k], q8[k]);
    }
    __syncthreads();
    for (int u = tid; u < C; u += 256) {
        atomicAdd(&stats[u], ls[u]);
        atomicAdd(&stats[C + u], ls[C + u]);
    }
}

__global__ void bnparam_k(const float* __restrict__ stats,
                          const float* __restrict__ g, const float* __restrict__ be,
                          float* __restrict__ sc, int C)
{
    int c = threadIdx.x;
    if (c >= C) return;
    const float invN = 1.f / (128.f * 4096.f);
    float mean  = stats[c] * invN;
    float var   = stats[C + c] * invN - mean * mean;
    float scale = g[c] * rsqrtf(var + 1e-5f);
    sc[c]     = scale;
    sc[C + c] = be[c] - mean * scale;
}

// ---------------------------------------------------------------------------
// Unified MFMA conv (fp16 single-precision-weights): CIN in-ch (BN_in+relu
// fused at staging), 64 out-ch per block. Block = 4 rows x 64 n, 4 waves,
// acc[4][4]. Act staged per 32-ch quarter (swizzled LDS, 25.3KB); B frags
// loaded straight from global (L2-resident) with 1-step register prefetch —
// no per-step barriers, only 2 per quarter-stage.
// grid: (2048 XCD-swizzled b*ytile blocks, NZ). n0e = n0 + blockIdx.y*64.
// ---------------------------------------------------------------------------
template<int CIN, bool CHUNK>
__global__ __launch_bounds__(256) void conv_mfma_k(
    const f16* __restrict__ in, const f16* __restrict__ wf,
    const float* __restrict__ scin, f16* __restrict__ outp,
    float* __restrict__ stats, int n0, int NG, int statsC, int ostride)
{
    constexpr int KQ = CIN / 32;
    constexpr int NSTEP = KQ * 9;
    __shared__ char actl[6*66*32*2];          // 25344
    __shared__ float lsts[4][64], lstq[4][64];
    // XCD-chunked swizzle: same-b y-tiles land on one XCD (halo L2 reuse)
    const int flat = blockIdx.x;
    const int swzb = (flat & 7) * 256 + (flat >> 3);
    const int b = swzb >> 4, y0 = (swzb & 15) * 4;
    const int n0e = n0 + blockIdx.y * 64;
    const int tid = threadIdx.x, l = tid & 63, w = tid >> 6;
    const int li = l & 15, g = l >> 4;

    f32x4 acc[4][4];
    #pragma unroll
    for (int mf = 0; mf < 4; ++mf)
        #pragma unroll
        for (int nf = 0; nf < 4; ++nf)
            acc[mf][nf] = f32x4{0.f, 0.f, 0.f, 0.f};

    int swz[3];
    #pragma unroll
    for (int dx = 0; dx < 3; ++dx) swz[dx] = ((li + dx) & 7) << 4;

    const f16* wblk = wf + ((size_t)(n0e >> 4) << 9) + (l << 3);
    auto bload = [&](int st, short8* dst) {
        int kq = st / 9, tap = st - kq * 9;
        int s = tap * KQ + kq;
        const f16* p = wblk + ((size_t)(s * NG) << 9);
        #pragma unroll
        for (int nf = 0; nf < 4; ++nf) dst[nf] = *(const short8*)(p + (nf << 9));
    };
    short8 breg[4], nbreg[4];
    bload(0, breg);

    for (int st = 0; st < NSTEP; ++st) {
        const int kq = st / 9, tap = st - kq * 9;
        if (tap == 0) {
            __syncthreads();
            // stage act quarter kq: rows y0-1..y0+4, ch [kq*32, kq*32+32)
            for (int u = tid; u < 6*66*4; u += 256) {
                int r = u / 264, rem = u - r * 264;
                int sx = rem >> 2, cg = rem & 3;
                int srow = y0 - 1 + r, gx = sx - 1;
                short8 pk = {0,0,0,0,0,0,0,0};
                if (srow >= 0 && srow < 64 && gx >= 0 && gx < 64) {
                    short8 raw = *(const short8*)(in +
                        ((size_t)(b*4096 + srow*64 + gx)) * CIN + kq*32 + cg*8);
                    #pragma unroll
                    for (int k = 0; k < 8; ++k) {
                        int c = kq*32 + cg*8 + k;
                        float v = fmaxf(fmaf(h2f(raw[k]), scin[c], scin[CIN + c]), 0.f);
                        pk[k] = f2h(v);
                    }
                }
                int off = ((r*66 + sx)*32 + cg*8)*2 ^ ((sx & 7) << 4);
                *(short8*)(actl + off) = pk;
            }
            __syncthreads();
        }
        if (st + 1 < NSTEP) bload(st + 1, nbreg);
        int dy = (tap * 11) >> 5, dx = tap - dy * 3;
        int r = w + dy;
        half8 a[4];
        #pragma unroll
        for (int mf = 0; mf < 4; ++mf) {
            int sx = mf*16 + li + dx;
            a[mf] = s2h8(*(const short8*)(actl + ((((r*66 + sx)*32) + g*8)*2 ^ swz[dx])));
        }
        #pragma unroll
        for (int nf = 0; nf < 4; ++nf) {
            half8 bb = s2h8(breg[nf]);
            #pragma unroll
            for (int mf = 0; mf < 4; ++mf)
                acc[mf][nf] = __builtin_amdgcn_mfma_f32_16x16x32_f16(a[mf], bb, acc[mf][nf], 0, 0, 0);
        }
        #pragma unroll
        for (int nf = 0; nf < 4; ++nf) breg[nf] = nbreg[nf];
    }

    // ---- stats epilogue (pre-BN sums): reduce over px, accumulate global
    #pragma unroll
    for (int nf = 0; nf < 4; ++nf) {
        float s = 0.f, q = 0.f;
        #pragma unroll
        for (int mf = 0; mf < 4; ++mf)
            #pragma unroll
            for (int reg = 0; reg < 4; ++reg) {
                float v = acc[mf][nf][reg];
                s += v; q += v * v;
            }
        s += __shfl_xor(s, 16); s += __shfl_xor(s, 32);
        q += __shfl_xor(q, 16); q += __shfl_xor(q, 32);
        if (l < 16) { lsts[w][nf*16 + l] = s; lstq[w][nf*16 + l] = q; }
    }
    __syncthreads();
    if (tid < 64) {
        const int sb = CHUNK ? 0 : n0e;
        float s = lsts[0][tid] + lsts[1][tid] + lsts[2][tid] + lsts[3][tid];
        float q = lstq[0][tid] + lstq[1][tid] + lstq[2][tid] + lstq[3][tid];
        atomicAdd(&stats[sb + tid], s);
        atomicAdd(&stats[statsC + sb + tid], q);
    }

    // ---- store fp16
    size_t rowbase = (size_t)b * 4096 + (size_t)(y0 + w) * 64;
    const int obase = CHUNK ? 0 : n0e;
    #pragma unroll
    for (int mf = 0; mf < 4; ++mf)
        #pragma unroll
        for (int nf = 0; nf < 4; ++nf) {
            int n = obase + nf*16 + li;
            #pragma unroll
            for (int reg = 0; reg < 4; ++reg) {
                int xx = mf*16 + g*4 + reg;
                outp[(rowbase + xx) * ostride + n] = (f16)acc[mf][nf][reg];
            }
        }
}

// ---------------------------------------------------------------------------
// Pool chunk: BN+relu on fp16 chunk (64 ch), pu (row means, direct write),
// pv (col means, atomicAdd across 2 y-half blocks). grid (128, 2).
// ---------------------------------------------------------------------------
__global__ __launch_bounds__(256) void pool_k(
    const f16* __restrict__ t3c, const float* __restrict__ sc3c,
    float* __restrict__ pu, float* __restrict__ pv, int ncb)
{
    const int b = blockIdx.x, yh = blockIdx.y;
    const int t = threadIdx.x, cg = t & 7, xp = t >> 3;
    const int w = t >> 6, lane = t & 63;
    __shared__ float rq[4][16][64];
    float scl[8], shf[8];
    #pragma unroll
    for (int k = 0; k < 8; ++k) { scl[k] = sc3c[cg*8 + k]; shf[k] = sc3c[64 + cg*8 + k]; }
    float colacc[2][8];
    #pragma unroll
    for (int xi = 0; xi < 2; ++xi)
        #pragma unroll
        for (int k = 0; k < 8; ++k) colacc[xi][k] = 0.f;

    for (int yb = 0; yb < 2; ++yb) {
        for (int yy = 0; yy < 16; ++yy) {
            int y = yh*32 + yb*16 + yy;
            float rc[8];
            #pragma unroll
            for (int xi = 0; xi < 2; ++xi) {
                int xx = xp*2 + xi;
                short8 raw = *(const short8*)(t3c +
                    ((size_t)(b*4096 + y*64 + xx)) * 64 + cg*8);
                #pragma unroll
                for (int k = 0; k < 8; ++k) {
                    float v = fmaxf(fmaf(h2f(raw[k]), scl[k], shf[k]), 0.f);
                    colacc[xi][k] += v;
                    rc[k] = xi ? (rc[k] + v) : v;
                }
            }
            #pragma unroll
            for (int k = 0; k < 8; ++k) {
                rc[k] += __shfl_xor(rc[k], 8);
                rc[k] += __shfl_xor(rc[k], 16);
                rc[k] += __shfl_xor(rc[k], 32);
            }
            if (lane < 8) {
                #pragma unroll
                for (int k = 0; k < 8; ++k) rq[w][yy][lane*8 + k] = rc[k];
            }
        }
        __syncthreads();
        for (int u = t; u < 1024; u += 256) {
            int yy = u >> 6, c = u & 63;
            float v = rq[0][yy][c] + rq[1][yy][c] + rq[2][yy][c] + rq[3][yy][c];
            pu[((size_t)b*256 + ncb + c)*64 + (yh*32 + yb*16 + yy)] = v * (1.f/64.f);
        }
        __syncthreads();
    }
    #pragma unroll
    for (int xi = 0; xi < 2; ++xi)
        #pragma unroll
        for (int k = 0; k < 8; ++k)
            atomicAdd(&pv[((size_t)b*256 + ncb + cg*8 + k)*64 + xp*2 + xi],
                      colacc[xi][k] * (1.f/64.f));
}

// ---------------------------------------------------------------------------
// u/v head: out[b][o][m] = relu(sum_c pool[b][c][m] * w[o][c] + bias[o])
// ---------------------------------------------------------------------------
__global__ __launch_bounds__(256) void headuv_k(
    const float* __restrict__ pool, const float* __restrict__ w,
    const float* __restrict__ bias, float* __restrict__ out)
{
    int b = blockIdx.x;
    int m = threadIdx.x & 63;
    int ob4 = threadIdx.x >> 6;
    float acc[4] = { bias[ob4], bias[ob4+4], bias[ob4+8], bias[ob4+12] };
    const float* pb = pool + (size_t)b * 256 * 64 + m;
    for (int c = 0; c < 256; ++c) {
        float v = pb[c * 64];
        #pragma unroll
        for (int i = 0; i < 4; ++i)
            acc[i] = fmaf(v, w[(ob4 + i*4) * 256 + c], acc[i]);
    }
    float* op = out + (size_t)b * 16 * 64 + m;
    #pragma unroll
    for (int i = 0; i < 4; ++i)
        op[(ob4 + i*4) * 64] = fmaxf(acc[i], 0.f);
}

// s head: ps derived from pu (ps[b][c] = mean_m pu[b][c][m]); 1 wave per b.
__global__ __launch_bounds__(64) void heads_s_k(
    const float* __restrict__ pu, const float* __restrict__ wS,
    const float* __restrict__ bS, float* __restrict__ out)
{
    int b = blockIdx.x, lane = threadIdx.x;
    __shared__ float ls[256];
    for (int i = 0; i < 4; ++i) {
        const float* p = pu + ((size_t)b*256 + lane*4 + i) * 64;
        float s = 0.f;
        for (int m = 0; m < 64; ++m) s += p[m];
        ls[lane*4 + i] = s * (1.f/64.f);
    }
    __syncthreads();
    float acc[8] = {0,0,0,0,0,0,0,0};
    for (int c = lane; c < 256; c += 64) {
        float v = ls[c];
        #pragma unroll
        for (int o = 0; o < 8; ++o) acc[o] = fmaf(v, wS[o*256 + c], acc[o]);
    }
    #pragma unroll
    for (int o = 0; o < 8; ++o) acc[o] = wave_sum(acc[o]);
    if (lane == 0) {
        #pragma unroll
        for (int o = 0; o < 8; ++o)
            out[b*8 + o] = fmaxf(acc[o] + bS[o], 0.f);
    }
}

// ---------------------------------------------------------------------------
// Gram-Schmidt: one wave per batch, lane = m. pre: (B,16,64), out: (B,64,8,2)
// ---------------------------------------------------------------------------
__global__ __launch_bounds__(64) void gs_k(
    const float* __restrict__ pre, float* __restrict__ out)
{
    int b = blockIdx.x, lane = threadIdx.x;
    const float* pb = pre + (size_t)b * 16 * 64 + lane;
    float vr[8], vi[8], den[8];
    #pragma unroll
    for (int j = 0; j < 8; ++j) { vr[j] = pb[(2*j)*64]; vi[j] = pb[(2*j+1)*64]; }

    #pragma unroll
    for (int j = 0; j < 8; ++j) {
        #pragma unroll
        for (int k = 0; k < j; ++k) {
            float d = wave_sum(vr[j]*vr[k] + vi[j]*vi[k]);
            float coef = d / den[k];
            vr[j] = fmaf(-coef, vr[k], vr[j]);
            vi[j] = fmaf(-coef, vi[k], vi[j]);
        }
        float n2 = wave_sum(vr[j]*vr[j] + vi[j]*vi[j]);
        float inv = 1.f / sqrtf(n2 + 1e-8f);
        vr[j] *= inv; vi[j] *= inv;
        float nn = wave_sum(vr[j]*vr[j] + vi[j]*vi[j]);
        den[j] = nn + 1e-8f;
    }
    float* ob = out + (size_t)b * 64 * 16 + lane * 16;
    #pragma unroll
    for (int j = 0; j < 8; ++j) { ob[j*2] = vr[j]; ob[j*2+1] = vi[j]; }
}

// ---------------------------------------------------------------------------
extern "C" void kernel_launch(void* const* d_in, const int* in_sizes, int n_in,
                              void* d_out, int out_size, void* d_ws, size_t ws_size,
                              hipStream_t stream)
{
    const float* x   = (const float*)d_in[0];
    const float* w1r = (const float*)d_in[1];
    const float* w1i = (const float*)d_in[3];
    const float* g1  = (const float*)d_in[5];
    const float* be1 = (const float*)d_in[6];
    const float* w2r = (const float*)d_in[7];
    const float* w2i = (const float*)d_in[9];
    const float* g2  = (const float*)d_in[11];
    const float* be2 = (const float*)d_in[12];
    const float* w3r = (const float*)d_in[13];
    const float* w3i = (const float*)d_in[15];
    const float* g3  = (const float*)d_in[17];
    const float* be3 = (const float*)d_in[18];
    const float* wu  = (const float*)d_in[19];
    const float* bu  = (const float*)d_in[20];
    const float* wS  = (const float*)d_in[21];
    const float* bS  = (const float*)d_in[22];
    const float* wv  = (const float*)d_in[23];
    const float* bv  = (const float*)d_in[24];
    float* out = (float*)d_out;

    char* ws = (char*)d_ws;
    // Layout, total 219,290,624 B == proven-safe footprint (r2-r4).
    f16*   t2     = (f16*)  (ws + 0);            // 134,217,728
    f16*   t1     = (f16*)  (ws + 134217728);    //  67,108,864 (dead after conv2)
    f16*   t3c    = (f16*)  (ws + 134217728);    //  67,108,864 (overlays t1)
    float* upre   = (float*)(ws + 134217728);    // 524,288 (after pools; t3c dead)
    float* vpre   = (float*)(ws + 134742016);    // 524,288
    float* pu     = (float*)(ws + 201326592);    //   8,388,608
    float* pv     = (float*)(ws + 209715200);    //   8,388,608
    // wreg region: wfrag2 (147,456 B) then wfrag3 (589,824 B)
    f16*   wfrag2 = (f16*)  (ws + 218103808);
    f16*   wfrag3 = (f16*)  (ws + 218103808);    // ends < 219,283,456
    float* stats  = (float*)(ws + 219283456);    // 512 floats
    float* scsh   = (float*)(ws + 219285504);    // 512 floats
    float* stats1 = stats,  *stats2 = stats + 128, *stats3c = stats + 384;
    float* sc1    = scsh,   *sc2    = scsh  + 128, *sc3c    = scsh  + 384;

    hipMemsetAsync(stats, 0, 2048, stream);
    hipMemsetAsync(pv, 0, (size_t)128*256*64*4, stream);

    // ---- weight prep for conv2 (9*2*8*512 = 73728 elems)
    prep_w_k<<<288, 256, 0, stream>>>(w2r, w2i, wfrag2, 64, 64);

    // ---- layer 1
    conv1_k<<<2048, 256, 0, stream>>>(x, w1r, w1i, t1);
    statsv_k<8><<<1024, 256, 0, stream>>>(t1, stats1, 16);
    bnparam_k<<<1, 64, 0, stream>>>(stats1, g1, be1, sc1, 64);

    // ---- layer 2 (BN1+relu fused in staging; stats fused in epilogue)
    conv_mfma_k<64, false><<<dim3(2048, 2), 256, 0, stream>>>(
        t1, wfrag2, sc1, t2, stats2,
        /*n0=*/0, /*NG=*/8, /*statsC=*/128, /*ostride=*/128);
    bnparam_k<<<1, 128, 0, stream>>>(stats2, g2, be2, sc2, 128);

    // ---- layer 3: conv once, 4 chunks of 64 out-ch (chunk in fp16)
    prep_w_k<<<1152, 256, 0, stream>>>(w3r, w3i, wfrag3, 128, 128);
    for (int nc = 0; nc < 4; ++nc) {
        hipMemsetAsync(stats3c, 0, 512, stream);
        conv_mfma_k<128, true><<<dim3(2048, 1), 256, 0, stream>>>(
            t2, wfrag3, sc2, t3c, stats3c,
            /*n0=*/nc*64, /*NG=*/16, /*statsC=*/64, /*ostride=*/64);
        bnparam_k<<<1, 64, 0, stream>>>(stats3c, g3 + nc*64, be3 + nc*64, sc3c, 64);
        pool_k<<<dim3(128, 2), 256, 0, stream>>>(t3c, sc3c, pu, pv, nc*64);
    }

    // ---- heads
    headuv_k<<<128, 256, 0, stream>>>(pu, wu, bu, upre);
    headuv_k<<<128, 256, 0, stream>>>(pv, wv, bv, vpre);
    heads_s_k<<<128, 64, 0, stream>>>(pu, wS, bS, out + 131072);

    // ---- gram-schmidt
    gs_k<<<128, 64, 0, stream>>>(upre, out);            // u at [0, 131072)
    gs_k<<<128, 64, 0, stream>>>(vpre, out + 132096);   // v at [132096, 263168)
}

// Round 6
// 838.932 us; speedup vs baseline: 16.4979x; 1.1885x over previous
//
#include <hip/hip_runtime.h>

typedef _Float16 f16;
typedef __attribute__((ext_vector_type(8))) short short8;
typedef __attribute__((ext_vector_type(8))) _Float16 half8;
typedef __attribute__((ext_vector_type(4))) float f32x4;

#define DEV __device__ __forceinline__

DEV float h2f(short s) { f16 h; __builtin_memcpy(&h, &s, 2); return (float)h; }
DEV short f2h(float f) { f16 h = (f16)f; short s; __builtin_memcpy(&s, &h, 2); return s; }
DEV half8 s2h8(short8 s) { half8 h; __builtin_memcpy(&h, &s, 16); return h; }

DEV float wave_sum(float v) {
    #pragma unroll
    for (int m = 1; m < 64; m <<= 1) v += __shfl_xor(v, m);
    return v;
}

// ---------------------------------------------------------------------------
// Weight prep: fold complex conv (wA = wr-wi for n<COUT, wB = wr+wi), fp16,
// MFMA fragment order: flat = ((s*NG+gg)*64+lane)*8+j, s = tap*KC+kc,
// n = gg*16+(lane&15), cin = kc*32+(lane>>4)*8+j. Conv biases dropped (BN
// cancels them exactly).
// ---------------------------------------------------------------------------
__global__ __launch_bounds__(256) void prep_w_k(
    const float* __restrict__ wr, const float* __restrict__ wi,
    f16* __restrict__ wf, int CIN, int COUT)
{
    int idx = blockIdx.x * 256 + threadIdx.x;
    int KC = CIN >> 5, NG = (2 * COUT) >> 4;
    int total = 9 * KC * NG * 512;
    if (idx >= total) return;
    int j = idx & 7, lane = (idx >> 3) & 63;
    int t9 = idx >> 9;
    int gg = t9 % NG, s = t9 / NG;
    int kc = s % KC, tap = s / KC;
    int n = gg * 16 + (lane & 15);
    int cin = kc * 32 + (lane >> 4) * 8 + j;
    int o = n < COUT ? n : n - COUT;
    float sgn = n < COUT ? -1.f : 1.f;
    float wv = wr[(o * CIN + cin) * 9 + tap] + sgn * wi[(o * CIN + cin) * 9 + tap];
    wf[idx] = (f16)wv;
}

// ---------------------------------------------------------------------------
// conv1: 2 -> 64 channels, fp32 VALU, NHWC fp16 output. No bias (BN removes).
// ---------------------------------------------------------------------------
__global__ __launch_bounds__(256) void conv1_k(
    const float* __restrict__ x,
    const float* __restrict__ w1r, const float* __restrict__ w1i,
    f16* __restrict__ out)
{
    int idx = blockIdx.x * 256 + threadIdx.x;      // b*4096 + m*64 + n
    int b = idx >> 12, p = idx & 4095;
    int m = p >> 6, n = p & 63;

    float v[2][9];
    #pragma unroll
    for (int dy = 0; dy < 3; ++dy)
        #pragma unroll
        for (int dx = 0; dx < 3; ++dx) {
            int yy = m + dy - 1, xx = n + dx - 1;
            bool ok = (yy >= 0 && yy < 64 && xx >= 0 && xx < 64);
            int base = ((b * 64 + (ok ? yy : 0)) * 64 + (ok ? xx : 0)) * 2;
            v[0][dy*3+dx] = ok ? x[base]     : 0.f;
            v[1][dy*3+dx] = ok ? x[base + 1] : 0.f;
        }

    float o1[64];
    #pragma unroll
    for (int o = 0; o < 32; ++o) {
        float cr = 0.f, ci = 0.f;
        #pragma unroll
        for (int c = 0; c < 2; ++c)
            #pragma unroll
            for (int k = 0; k < 9; ++k) {
                cr = fmaf(v[c][k], w1r[(o*2+c)*9 + k], cr);
                ci = fmaf(v[c][k], w1i[(o*2+c)*9 + k], ci);
            }
        o1[o]      = cr - ci;
        o1[32 + o] = cr + ci;
    }
    f16* ob = out + (size_t)idx * 64;
    #pragma unroll
    for (int grp = 0; grp < 8; ++grp) {
        short8 pk;
        #pragma unroll
        for (int k = 0; k < 8; ++k) pk[k] = f2h(o1[grp*8 + k]);
        *(short8*)(ob + grp * 8) = pk;
    }
}

// ---------------------------------------------------------------------------
// Per-channel sum/sumsq over NHWC fp16, vectorized x8. C8 = C/8.
// ---------------------------------------------------------------------------
template<int C8>
__global__ __launch_bounds__(256) void statsv_k(
    const f16* __restrict__ t, float* __restrict__ stats, int iters)
{
    const int C = C8 * 8;
    __shared__ float ls[2 * C];
    const int tid = threadIdx.x;
    const int cg = tid & (C8 - 1), pg = tid / C8;
    const int NG = 256 / C8;
    for (int u = tid; u < 2 * C; u += 256) ls[u] = 0.f;
    __syncthreads();
    float s8[8] = {0,0,0,0,0,0,0,0}, q8[8] = {0,0,0,0,0,0,0,0};
    size_t base = (size_t)blockIdx.x * NG * iters + pg;
    for (int i = 0; i < iters; ++i) {
        size_t pp = base + (size_t)i * NG;
        short8 r = *(const short8*)(t + pp * C + cg * 8);
        #pragma unroll
        for (int k = 0; k < 8; ++k) { float v = h2f(r[k]); s8[k] += v; q8[k] += v * v; }
    }
    #pragma unroll
    for (int k = 0; k < 8; ++k) {
        atomicAdd(&ls[cg*8 + k], s8[k]);
        atomicAdd(&ls[C + cg*8 + k], q8[k]);
    }
    __syncthreads();
    for (int u = tid; u < C; u += 256) {
        atomicAdd(&stats[u], ls[u]);
        atomicAdd(&stats[C + u], ls[C + u]);
    }
}

__global__ void bnparam_k(const float* __restrict__ stats,
                          const float* __restrict__ g, const float* __restrict__ be,
                          float* __restrict__ sc, int C)
{
    int c = threadIdx.x;
    if (c >= C) return;
    const float invN = 1.f / (128.f * 4096.f);
    float mean  = stats[c] * invN;
    float var   = stats[C + c] * invN - mean * mean;
    float scale = g[c] * rsqrtf(var + 1e-5f);
    sc[c]     = scale;
    sc[C + c] = be[c] - mean * scale;
}

// ---------------------------------------------------------------------------
// Unified MFMA conv (fp16): CIN in-ch (BN_in+relu fused at staging, packed
// f16 math), 64 out-ch per block. Block = 4 rows x 64 n, 4 waves, acc[4][4].
// Act staged per 32-ch quarter (swizzled LDS); B frags direct from global
// (L2-resident), no prefetch — latency hidden by occupancy (reg diet to
// <=128 incl AGPRs -> 4 waves/SIMD, enforced via __launch_bounds__(256,4)).
// grid: (2048 XCD-swizzled b*ytile blocks, NZ). n0e = n0 + blockIdx.y*64.
// ---------------------------------------------------------------------------
template<int CIN, bool CHUNK>
__global__ __launch_bounds__(256, 4) void conv_mfma_k(
    const f16* __restrict__ in, const f16* __restrict__ wf,
    const float* __restrict__ scin, f16* __restrict__ outp,
    float* __restrict__ stats, int n0, int NG, int statsC, int ostride)
{
    constexpr int KQ = CIN / 32;
    constexpr int NSTEP = KQ * 9;
    __shared__ char actl[6*66*32*2];          // 25344
    __shared__ float lsts[4][64], lstq[4][64];
    // XCD-chunked swizzle: same-b y-tiles land on one XCD (halo L2 reuse)
    const int flat = blockIdx.x;
    const int swzb = (flat & 7) * 256 + (flat >> 3);
    const int b = swzb >> 4, y0 = (swzb & 15) * 4;
    const int n0e = n0 + blockIdx.y * 64;
    const int tid = threadIdx.x, l = tid & 63, w = tid >> 6;
    const int li = l & 15, g = l >> 4;

    f32x4 acc[4][4];
    #pragma unroll
    for (int mf = 0; mf < 4; ++mf)
        #pragma unroll
        for (int nf = 0; nf < 4; ++nf)
            acc[mf][nf] = f32x4{0.f, 0.f, 0.f, 0.f};

    int swz[3];
    #pragma unroll
    for (int dx = 0; dx < 3; ++dx) swz[dx] = ((li + dx) & 7) << 4;

    const f16* wblk = wf + ((size_t)(n0e >> 4) << 9) + (l << 3);

    for (int st = 0; st < NSTEP; ++st) {
        const int kq = st / 9, tap = st - kq * 9;
        if (tap == 0) {
            // hoist this thread's BN params (cg = tid&3 is iteration-invariant)
            half8 scl8, shf8;
            {
                int cb = kq*32 + (tid & 3) * 8;
                #pragma unroll
                for (int k = 0; k < 8; ++k) {
                    scl8[k] = (f16)scin[cb + k];
                    shf8[k] = (f16)scin[CIN + cb + k];
                }
            }
            __syncthreads();
            // stage act quarter kq: rows y0-1..y0+4, ch [kq*32, kq*32+32)
            #pragma unroll
            for (int i = 0; i < 7; ++i) {
                int u = tid + i * 256;
                if (u < 6*66*4) {
                    int r = u / 264, rem = u - r * 264;
                    int sx = rem >> 2, cg = rem & 3;
                    int srow = y0 - 1 + r, gx = sx - 1;
                    short8 pk = {0,0,0,0,0,0,0,0};
                    if (srow >= 0 && srow < 64 && gx >= 0 && gx < 64) {
                        short8 raw = *(const short8*)(in +
                            ((size_t)(b*4096 + srow*64 + gx)) * CIN + kq*32 + cg*8);
                        half8 rv = s2h8(raw) * scl8 + shf8;   // v_pk_fma_f16
                        short8 sr; __builtin_memcpy(&sr, &rv, 16);
                        pk = sr & ~(sr >> 15);                // packed relu
                    }
                    int off = ((r*66 + sx)*32 + cg*8)*2 ^ ((sx & 7) << 4);
                    *(short8*)(actl + off) = pk;
                }
            }
            __syncthreads();
        }
        // B fragments straight from global (L2-resident weights)
        short8 breg[4];
        {
            int s = tap * KQ + kq;
            const f16* p = wblk + ((size_t)(s * NG) << 9);
            #pragma unroll
            for (int nf = 0; nf < 4; ++nf) breg[nf] = *(const short8*)(p + (nf << 9));
        }
        int dy = (tap * 11) >> 5, dx = tap - dy * 3;
        int r = w + dy;
        #pragma unroll
        for (int mf = 0; mf < 4; ++mf) {
            int sx = mf*16 + li + dx;
            half8 a = s2h8(*(const short8*)(actl + ((((r*66 + sx)*32) + g*8)*2 ^ swz[dx])));
            #pragma unroll
            for (int nf = 0; nf < 4; ++nf)
                acc[mf][nf] = __builtin_amdgcn_mfma_f32_16x16x32_f16(a, s2h8(breg[nf]), acc[mf][nf], 0, 0, 0);
        }
    }

    // ---- stats epilogue (pre-BN sums): reduce over px, accumulate global
    #pragma unroll
    for (int nf = 0; nf < 4; ++nf) {
        float s = 0.f, q = 0.f;
        #pragma unroll
        for (int mf = 0; mf < 4; ++mf)
            #pragma unroll
            for (int reg = 0; reg < 4; ++reg) {
                float v = acc[mf][nf][reg];
                s += v; q += v * v;
            }
        s += __shfl_xor(s, 16); s += __shfl_xor(s, 32);
        q += __shfl_xor(q, 16); q += __shfl_xor(q, 32);
        if (l < 16) { lsts[w][nf*16 + l] = s; lstq[w][nf*16 + l] = q; }
    }
    __syncthreads();
    if (tid < 64) {
        const int sb = CHUNK ? 0 : n0e;
        float s = lsts[0][tid] + lsts[1][tid] + lsts[2][tid] + lsts[3][tid];
        float q = lstq[0][tid] + lstq[1][tid] + lstq[2][tid] + lstq[3][tid];
        atomicAdd(&stats[sb + tid], s);
        atomicAdd(&stats[statsC + sb + tid], q);
    }

    // ---- store fp16
    size_t rowbase = (size_t)b * 4096 + (size_t)(y0 + w) * 64;
    const int obase = CHUNK ? 0 : n0e;
    #pragma unroll
    for (int mf = 0; mf < 4; ++mf)
        #pragma unroll
        for (int nf = 0; nf < 4; ++nf) {
            int n = obase + nf*16 + li;
            #pragma unroll
            for (int reg = 0; reg < 4; ++reg) {
                int xx = mf*16 + g*4 + reg;
                outp[(rowbase + xx) * ostride + n] = (f16)acc[mf][nf][reg];
            }
        }
}

// ---------------------------------------------------------------------------
// Pool chunk: BN+relu on fp16 chunk (64 ch), pu (row means, direct write),
// pv (col means, atomicAdd across 2 y-half blocks). grid (128, 2).
// ---------------------------------------------------------------------------
__global__ __launch_bounds__(256) void pool_k(
    const f16* __restrict__ t3c, const float* __restrict__ sc3c,
    float* __restrict__ pu, float* __restrict__ pv, int ncb)
{
    const int b = blockIdx.x, yh = blockIdx.y;
    const int t = threadIdx.x, cg = t & 7, xp = t >> 3;
    const int w = t >> 6, lane = t & 63;
    __shared__ float rq[4][16][64];
    float scl[8], shf[8];
    #pragma unroll
    for (int k = 0; k < 8; ++k) { scl[k] = sc3c[cg*8 + k]; shf[k] = sc3c[64 + cg*8 + k]; }
    float colacc[2][8];
    #pragma unroll
    for (int xi = 0; xi < 2; ++xi)
        #pragma unroll
        for (int k = 0; k < 8; ++k) colacc[xi][k] = 0.f;

    for (int yb = 0; yb < 2; ++yb) {
        for (int yy = 0; yy < 16; ++yy) {
            int y = yh*32 + yb*16 + yy;
            float rc[8];
            #pragma unroll
            for (int xi = 0; xi < 2; ++xi) {
                int xx = xp*2 + xi;
                short8 raw = *(const short8*)(t3c +
                    ((size_t)(b*4096 + y*64 + xx)) * 64 + cg*8);
                #pragma unroll
                for (int k = 0; k < 8; ++k) {
                    float v = fmaxf(fmaf(h2f(raw[k]), scl[k], shf[k]), 0.f);
                    colacc[xi][k] += v;
                    rc[k] = xi ? (rc[k] + v) : v;
                }
            }
            #pragma unroll
            for (int k = 0; k < 8; ++k) {
                rc[k] += __shfl_xor(rc[k], 8);
                rc[k] += __shfl_xor(rc[k], 16);
                rc[k] += __shfl_xor(rc[k], 32);
            }
            if (lane < 8) {
                #pragma unroll
                for (int k = 0; k < 8; ++k) rq[w][yy][lane*8 + k] = rc[k];
            }
        }
        __syncthreads();
        for (int u = t; u < 1024; u += 256) {
            int yy = u >> 6, c = u & 63;
            float v = rq[0][yy][c] + rq[1][yy][c] + rq[2][yy][c] + rq[3][yy][c];
            pu[((size_t)b*256 + ncb + c)*64 + (yh*32 + yb*16 + yy)] = v * (1.f/64.f);
        }
        __syncthreads();
    }
    #pragma unroll
    for (int xi = 0; xi < 2; ++xi)
        #pragma unroll
        for (int k = 0; k < 8; ++k)
            atomicAdd(&pv[((size_t)b*256 + ncb + cg*8 + k)*64 + xp*2 + xi],
                      colacc[xi][k] * (1.f/64.f));
}

// ---------------------------------------------------------------------------
// u/v head: out[b][o][m] = relu(sum_c pool[b][c][m] * w[o][c] + bias[o])
// ---------------------------------------------------------------------------
__global__ __launch_bounds__(256) void headuv_k(
    const float* __restrict__ pool, const float* __restrict__ w,
    const float* __restrict__ bias, float* __restrict__ out)
{
    int b = blockIdx.x;
    int m = threadIdx.x & 63;
    int ob4 = threadIdx.x >> 6;
    float acc[4] = { bias[ob4], bias[ob4+4], bias[ob4+8], bias[ob4+12] };
    const float* pb = pool + (size_t)b * 256 * 64 + m;
    for (int c = 0; c < 256; ++c) {
        float v = pb[c * 64];
        #pragma unroll
        for (int i = 0; i < 4; ++i)
            acc[i] = fmaf(v, w[(ob4 + i*4) * 256 + c], acc[i]);
    }
    float* op = out + (size_t)b * 16 * 64 + m;
    #pragma unroll
    for (int i = 0; i < 4; ++i)
        op[(ob4 + i*4) * 64] = fmaxf(acc[i], 0.f);
}

// s head: ps derived from pu (ps[b][c] = mean_m pu[b][c][m]); 1 wave per b.
__global__ __launch_bounds__(64) void heads_s_k(
    const float* __restrict__ pu, const float* __restrict__ wS,
    const float* __restrict__ bS, float* __restrict__ out)
{
    int b = blockIdx.x, lane = threadIdx.x;
    __shared__ float ls[256];
    for (int i = 0; i < 4; ++i) {
        const float* p = pu + ((size_t)b*256 + lane*4 + i) * 64;
        float s = 0.f;
        for (int m = 0; m < 64; ++m) s += p[m];
        ls[lane*4 + i] = s * (1.f/64.f);
    }
    __syncthreads();
    float acc[8] = {0,0,0,0,0,0,0,0};
    for (int c = lane; c < 256; c += 64) {
        float v = ls[c];
        #pragma unroll
        for (int o = 0; o < 8; ++o) acc[o] = fmaf(v, wS[o*256 + c], acc[o]);
    }
    #pragma unroll
    for (int o = 0; o < 8; ++o) acc[o] = wave_sum(acc[o]);
    if (lane == 0) {
        #pragma unroll
        for (int o = 0; o < 8; ++o)
            out[b*8 + o] = fmaxf(acc[o] + bS[o], 0.f);
    }
}

// ---------------------------------------------------------------------------
// Gram-Schmidt: one wave per batch, lane = m. pre: (B,16,64), out: (B,64,8,2)
// ---------------------------------------------------------------------------
__global__ __launch_bounds__(64) void gs_k(
    const float* __restrict__ pre, float* __restrict__ out)
{
    int b = blockIdx.x, lane = threadIdx.x;
    const float* pb = pre + (size_t)b * 16 * 64 + lane;
    float vr[8], vi[8], den[8];
    #pragma unroll
    for (int j = 0; j < 8; ++j) { vr[j] = pb[(2*j)*64]; vi[j] = pb[(2*j+1)*64]; }

    #pragma unroll
    for (int j = 0; j < 8; ++j) {
        #pragma unroll
        for (int k = 0; k < j; ++k) {
            float d = wave_sum(vr[j]*vr[k] + vi[j]*vi[k]);
            float coef = d / den[k];
            vr[j] = fmaf(-coef, vr[k], vr[j]);
            vi[j] = fmaf(-coef, vi[k], vi[j]);
        }
        float n2 = wave_sum(vr[j]*vr[j] + vi[j]*vi[j]);
        float inv = 1.f / sqrtf(n2 + 1e-8f);
        vr[j] *= inv; vi[j] *= inv;
        float nn = wave_sum(vr[j]*vr[j] + vi[j]*vi[j]);
        den[j] = nn + 1e-8f;
    }
    float* ob = out + (size_t)b * 64 * 16 + lane * 16;
    #pragma unroll
    for (int j = 0; j < 8; ++j) { ob[j*2] = vr[j]; ob[j*2+1] = vi[j]; }
}

// ---------------------------------------------------------------------------
extern "C" void kernel_launch(void* const* d_in, const int* in_sizes, int n_in,
                              void* d_out, int out_size, void* d_ws, size_t ws_size,
                              hipStream_t stream)
{
    const float* x   = (const float*)d_in[0];
    const float* w1r = (const float*)d_in[1];
    const float* w1i = (const float*)d_in[3];
    const float* g1  = (const float*)d_in[5];
    const float* be1 = (const float*)d_in[6];
    const float* w2r = (const float*)d_in[7];
    const float* w2i = (const float*)d_in[9];
    const float* g2  = (const float*)d_in[11];
    const float* be2 = (const float*)d_in[12];
    const float* w3r = (const float*)d_in[13];
    const float* w3i = (const float*)d_in[15];
    const float* g3  = (const float*)d_in[17];
    const float* be3 = (const float*)d_in[18];
    const float* wu  = (const float*)d_in[19];
    const float* bu  = (const float*)d_in[20];
    const float* wS  = (const float*)d_in[21];
    const float* bS  = (const float*)d_in[22];
    const float* wv  = (const float*)d_in[23];
    const float* bv  = (const float*)d_in[24];
    float* out = (float*)d_out;

    char* ws = (char*)d_ws;
    // Layout, total 219,290,624 B == proven-safe footprint (r2-r5).
    f16*   t2     = (f16*)  (ws + 0);            // 134,217,728
    f16*   t1     = (f16*)  (ws + 134217728);    //  67,108,864 (dead after conv2)
    f16*   t3c    = (f16*)  (ws + 134217728);    //  67,108,864 (overlays t1)
    float* upre   = (float*)(ws + 134217728);    // 524,288 (after pools; t3c dead)
    float* vpre   = (float*)(ws + 134742016);    // 524,288
    float* pu     = (float*)(ws + 201326592);    //   8,388,608
    float* pv     = (float*)(ws + 209715200);    //   8,388,608
    // wreg region: wfrag2 (147,456 B) then wfrag3 (589,824 B)
    f16*   wfrag2 = (f16*)  (ws + 218103808);
    f16*   wfrag3 = (f16*)  (ws + 218103808);    // ends < 219,283,456
    float* stats  = (float*)(ws + 219283456);    // 896 floats (3584 B)
    float* scsh   = (float*)(ws + 219287040);    // 512 floats
    // stats layout: s1 [0,128), s2 [128,384), s3 chunk nc at [384+nc*128)
    float* stats1 = stats,  *stats2 = stats + 128;
    float* sc1    = scsh,   *sc2    = scsh  + 128, *sc3c = scsh + 384;

    hipMemsetAsync(stats, 0, 3584, stream);
    hipMemsetAsync(pv, 0, (size_t)128*256*64*4, stream);

    // ---- weight prep for conv2 (9*2*8*512 = 73728 elems)
    prep_w_k<<<288, 256, 0, stream>>>(w2r, w2i, wfrag2, 64, 64);

    // ---- layer 1
    conv1_k<<<2048, 256, 0, stream>>>(x, w1r, w1i, t1);
    statsv_k<8><<<1024, 256, 0, stream>>>(t1, stats1, 16);
    bnparam_k<<<1, 64, 0, stream>>>(stats1, g1, be1, sc1, 64);

    // ---- layer 2 (BN1+relu fused in staging; stats fused in epilogue)
    conv_mfma_k<64, false><<<dim3(2048, 2), 256, 0, stream>>>(
        t1, wfrag2, sc1, t2, stats2,
        /*n0=*/0, /*NG=*/8, /*statsC=*/128, /*ostride=*/128);
    bnparam_k<<<1, 128, 0, stream>>>(stats2, g2, be2, sc2, 128);

    // ---- layer 3: conv once, 4 chunks of 64 out-ch (chunk in fp16)
    prep_w_k<<<1152, 256, 0, stream>>>(w3r, w3i, wfrag3, 128, 128);
    for (int nc = 0; nc < 4; ++nc) {
        conv_mfma_k<128, true><<<dim3(2048, 1), 256, 0, stream>>>(
            t2, wfrag3, sc2, t3c, stats + 384 + nc*128,
            /*n0=*/nc*64, /*NG=*/16, /*statsC=*/64, /*ostride=*/64);
        bnparam_k<<<1, 64, 0, stream>>>(stats + 384 + nc*128, g3 + nc*64, be3 + nc*64, sc3c, 64);
        pool_k<<<dim3(128, 2), 256, 0, stream>>>(t3c, sc3c, pu, pv, nc*64);
    }

    // ---- heads
    headuv_k<<<128, 256, 0, stream>>>(pu, wu, bu, upre);
    headuv_k<<<128, 256, 0, stream>>>(pv, wv, bv, vpre);
    heads_s_k<<<128, 64, 0, stream>>>(pu, wS, bS, out + 131072);

    // ---- gram-schmidt
    gs_k<<<128, 64, 0, stream>>>(upre, out);            // u at [0, 131072)
    gs_k<<<128, 64, 0, stream>>>(vpre, out + 132096);   // v at [132096, 263168)
}